// Round 5
// baseline (359.800 us; speedup 1.0000x reference)
//
#include <hip/hip_runtime.h>
#include <hip/hip_bf16.h>

// Problem dims (fixed by setup_inputs)
#define S   2048
#define D   1024
#define DFF 4096
#define NH  16
#define HD  64

typedef unsigned short u16;
typedef unsigned int   u32;
typedef __attribute__((ext_vector_type(8))) short      short8;  // 8 bf16
typedef __attribute__((ext_vector_type(4))) float      floatx4; // MFMA C/D
typedef __attribute__((ext_vector_type(2))) _Float16   half2v;
typedef __attribute__((ext_vector_type(4))) _Float16   half4v;
typedef __attribute__((ext_vector_type(8))) _Float16   half8v;

__device__ __forceinline__ float bu2f(u16 u) {
    union { u32 i; float f; } x; x.i = ((u32)u) << 16; return x.f;
}
__device__ __forceinline__ u16 f2bu(float f) {
    __hip_bfloat16 h = __float2bfloat16(f);
    return *(u16*)&h;
}
__device__ __forceinline__ u16 f2h(float f) {
    _Float16 h = (_Float16)f; return *(u16*)&h;
}
__device__ __forceinline__ float ldf(const float* p) { return *p; }
__device__ __forceinline__ float ldf(const u16* p)   { return bu2f(*p); }

// cvt_pkrtz returns __fp16x2; bit-cast to our _Float16x2 (same 32-bit reg)
__device__ __forceinline__ half2v pkrtz(float a, float b) {
    auto v = __builtin_amdgcn_cvt_pkrtz(a, b);
    union { decltype(v) i; half2v o; } u; u.i = v; return u.o;
}

__device__ __forceinline__ floatx4 mfma_f16(half8v a, half8v b, floatx4 c) {
    return __builtin_amdgcn_mfma_f32_16x16x32_f16(a, b, c, 0, 0, 0);
}
__device__ __forceinline__ float fdot2f(half2v a, half2v b, float c) {
#if __has_builtin(__builtin_amdgcn_fdot2)
    return __builtin_amdgcn_fdot2(a, b, c, false);
#else
    return c + (float)a[0] * (float)b[0] + (float)a[1] * (float)b[1];
#endif
}

// ---- DPP 16-lane row reductions (VALU-speed, replaces ds_swizzle chains) ----
template <int K>
__device__ __forceinline__ float ror16f(float v) {
    int s = __builtin_bit_cast(int, v);
    int r = __builtin_amdgcn_update_dpp(s, s, 0x120 | K, 0xF, 0xF, false);
    return __builtin_bit_cast(float, r);
}
__device__ __forceinline__ float rowsum16(float v) {
    v += ror16f<1>(v);
    v += ror16f<2>(v);
    v += ror16f<4>(v);
    v += ror16f<8>(v);
    return v;
}
__device__ __forceinline__ float rowmax16(float v) {
    v = fmaxf(v, ror16f<1>(v));
    v = fmaxf(v, ror16f<2>(v));
    v = fmaxf(v, ror16f<4>(v));
    v = fmaxf(v, ror16f<8>(v));
    return v;
}

// async global->LDS, 16B per lane, lands at ldsbase + lane*16
__device__ __forceinline__ void async16(const void* g, void* l) {
    __builtin_amdgcn_global_load_lds(
        (const __attribute__((address_space(1))) u32*)g,
        (__attribute__((address_space(3))) u32*)l, 16, 0, 0);
}

// ---------------- fp32 -> bf16 bulk convert (weights) ------------------------
__global__ __launch_bounds__(256)
void cvt_kernel(const float* __restrict__ in, u16* __restrict__ out, int n4)
{
    int i = blockIdx.x * 256 + threadIdx.x;
    if (i < n4) {
        float4 v = ((const float4*)in)[i];
        ushort4 s;
        s.x = f2bu(v.x); s.y = f2bu(v.y); s.z = f2bu(v.z); s.w = f2bu(v.w);
        ((ushort4*)out)[i] = s;
    }
}

// ---------------- key-compaction scan: newpos[] + nk from mask ---------------
// Unmasked keys -> [0, nk) (order-preserving), masked -> [nk, 2048).
// Attention is permutation-invariant over keys, and masked keys' P == 0.
__global__ __launch_bounds__(256)
void scan_mask_kernel(const int* __restrict__ mask, int* __restrict__ newpos,
                      int* __restrict__ nkbuf)
{
    __shared__ int ps[256];
    const int t = threadIdx.x;
    int loc[8];
    int s = 0;
#pragma unroll
    for (int j = 0; j < 8; j++) {
        loc[j] = s;
        s += (mask[t * 8 + j] != 0);
    }
    ps[t] = s;
    __syncthreads();
    for (int off = 1; off < 256; off <<= 1) {
        int v = (t >= off) ? ps[t - off] : 0;
        __syncthreads();
        ps[t] += v;
        __syncthreads();
    }
    const int total = ps[255];                 // nk
    const int base = t ? ps[t - 1] : 0;        // unmasked count before this chunk
#pragma unroll
    for (int j = 0; j < 8; j++) {
        const int gi = t * 8 + j;
        const int up = base + loc[j];          // unmasked rank
        newpos[gi] = mask[gi] ? up : (total + gi - up);
    }
    if (t == 0) nkbuf[0] = total;
}

// ---------------- LayerNorm: one block per row, D=1024, 256 threads ----------
template <typename T>
__global__ __launch_bounds__(256, 4)
void ln_kernel(const T* __restrict__ in, const float* __restrict__ ga,
               const float* __restrict__ gb, u16* __restrict__ out)
{
    const int row = blockIdx.x;
    const int t = threadIdx.x;
    const T* x = in + (size_t)row * D;
    float v[4];
    float s = 0.f, ss = 0.f;
#pragma unroll
    for (int j = 0; j < 4; j++) {
        float val = ldf(x + t + 256 * j);
        v[j] = val; s += val; ss = fmaf(val, val, ss);
    }
#pragma unroll
    for (int off = 32; off >= 1; off >>= 1) {
        s  += __shfl_down(s,  off, 64);
        ss += __shfl_down(ss, off, 64);
    }
    __shared__ float red[10];
    const int wave = t >> 6, lane = t & 63;
    if (lane == 0) { red[wave] = s; red[4 + wave] = ss; }
    __syncthreads();
    if (t == 0) {
        float S1 = red[0] + red[1] + red[2] + red[3];
        float S2 = red[4] + red[5] + red[6] + red[7];
        float mu = S1 / (float)D;
        float var = (S2 - (float)D * mu * mu) / (float)(D - 1);  // ddof=1
        float sig = sqrtf(fmaxf(var, 0.f)) + 1e-6f;              // eps on sigma
        red[8] = mu; red[9] = 1.f / sig;
    }
    __syncthreads();
    const float mu = red[8], rs = red[9];
#pragma unroll
    for (int j = 0; j < 4; j++) {
        int c = t + 256 * j;
        out[(size_t)row * D + c] = f2bu((v[j] - mu) * rs * ga[c] + gb[c]);
    }
}

// ======================= MFMA GEMM core (128x128 tile) =======================
#define GEMM_CORE(A_, B_, K_)                                                   \
    __shared__ u16 As[128 * 32];                                                \
    __shared__ u16 Bs[128 * 32];                                                \
    const int t = threadIdx.x;                                                  \
    const int w = t >> 6, l = t & 63;                                           \
    const int m0 = blockIdx.y * 128, n0 = blockIdx.x * 128;                     \
    const int qk = l >> 4, col = l & 15;                                        \
    const int wm = (w & 1) * 64, wn = (w >> 1) * 64;                            \
    const int sr  = l >> 2;                                                     \
    const int sq  = l & 3;                                                      \
    const int row = w * 16 + sr;                                                \
    const int gq  = sq ^ ((row >> 1) & 3);                                      \
    const u16* Ap = A_ + (size_t)(m0 + row) * K_ + gq * 8;                      \
    const u16* Bp = B_ + (size_t)(n0 + row) * K_ + gq * 8;                      \
    u16* AsW = As + w * 16 * 32;                                                \
    u16* BsW = Bs + w * 16 * 32;                                                \
    const int mloc = wm + col, nloc = wn + col;                                 \
    const u16* aBase = As + mloc * 32 + (qk ^ ((mloc >> 1) & 3)) * 8;           \
    const u16* bBase = Bs + nloc * 32 + (qk ^ ((nloc >> 1) & 3)) * 8;           \
    floatx4 acc[4][4];                                                          \
    _Pragma("unroll")                                                           \
    for (int i = 0; i < 4; i++)                                                 \
        _Pragma("unroll")                                                       \
        for (int j = 0; j < 4; j++) acc[i][j] = (floatx4)0.f;                   \
    for (int k0 = 0; k0 < K_; k0 += 32) {                                       \
        __syncthreads();                                                        \
        async16(Ap,                  AsW);                                      \
        async16(Ap + (size_t)64 * K_, AsW + 64 * 32);                           \
        async16(Bp,                  BsW);                                      \
        async16(Bp + (size_t)64 * K_, BsW + 64 * 32);                           \
        Ap += 32; Bp += 32;                                                     \
        __syncthreads();                                                        \
        short8 a[4], b[4];                                                      \
        _Pragma("unroll")                                                       \
        for (int i = 0; i < 4; i++) a[i] = *(const short8*)(aBase + i * 16 * 32);\
        _Pragma("unroll")                                                       \
        for (int j = 0; j < 4; j++) b[j] = *(const short8*)(bBase + j * 16 * 32);\
        _Pragma("unroll")                                                       \
        for (int i = 0; i < 4; i++)                                             \
            _Pragma("unroll")                                                   \
            for (int j = 0; j < 4; j++)                                         \
                acc[i][j] = __builtin_amdgcn_mfma_f32_16x16x32_bf16(            \
                    a[i], b[j], acc[i][j], 0, 0, 0);                            \
    }

// ---- generic GEMM 128x128 (+bias/relu/res), OMODE 0 f32 / 1 bf16 ------------
template <int OMODE, bool RELU, int RES>
__global__ __launch_bounds__(256, 2)
void gemm_mfma(const u16* __restrict__ A, const u16* __restrict__ B,
               const float* __restrict__ bias, const void* __restrict__ res,
               void* __restrict__ Cout, int M, int N, int K)
{
    GEMM_CORE(A, B, K)
#pragma unroll
    for (int j = 0; j < 4; j++) {
        const int n = n0 + wn + j * 16 + col;
        const float bn = bias[n];
#pragma unroll
        for (int i = 0; i < 4; i++) {
#pragma unroll
            for (int r = 0; r < 4; r++) {
                const int m = m0 + wm + i * 16 + qk * 4 + r;
                float v = acc[i][j][r] + bn;
                if (RELU) v = fmaxf(v, 0.f);
                if (RES == 1) v += ((const float*)res)[(size_t)m * N + n];
                if (RES == 2) v += bu2f(((const u16*)res)[(size_t)m * N + n]);
                if (OMODE == 0) ((float*)Cout)[(size_t)m * N + n] = v;
                if (OMODE == 1) ((u16*)Cout)[(size_t)m * N + n] = f2bu(v);
            }
        }
    }
}

// ---- fused QKV GEMM (128x128): f16 Q [S,D]; K,V^T written PERMUTED by np ----
__global__ __launch_bounds__(256, 2)
void gemm_qkv(const u16* __restrict__ A, const u16* __restrict__ B,
              const float* __restrict__ bq, const float* __restrict__ bk,
              const float* __restrict__ bv, const int* __restrict__ np,
              u16* __restrict__ outQ, u16* __restrict__ outK,
              u16* __restrict__ outVT)
{
    const int K = D;
    GEMM_CORE(A, B, K)
    const int seg   = n0 >> 10;
    const int nbase = n0 & 1023;
    const float* bs = (seg == 0) ? bq : (seg == 1) ? bk : bv;
    int npm[4][4];
    if (seg != 0) {
#pragma unroll
        for (int i = 0; i < 4; i++)
#pragma unroll
            for (int r = 0; r < 4; r++)
                npm[i][r] = np[m0 + wm + i * 16 + qk * 4 + r];
    }
#pragma unroll
    for (int j = 0; j < 4; j++) {
        const int nl = nbase + wn + j * 16 + col;
        const float bn = bs[nl];
#pragma unroll
        for (int i = 0; i < 4; i++) {
#pragma unroll
            for (int r = 0; r < 4; r++) {
                const int m = m0 + wm + i * 16 + qk * 4 + r;
                float v = acc[i][j][r] + bn;
                if (seg == 0)      outQ [(size_t)m * D + nl]          = f2h(v);
                else if (seg == 1) outK [(size_t)npm[i][r] * D + nl]  = f2h(v);
                else               outVT[(size_t)nl * S + npm[i][r]]  = f2h(v);
            }
        }
    }
}

// ---- 128x64-tile GEMM (2x the blocks for N=1024 outputs: WO, FFN2) ----------
template <int OMODE, int RES>
__global__ __launch_bounds__(256, 2)
void gemm_mfma64(const u16* __restrict__ A, const u16* __restrict__ B,
                 const float* __restrict__ bias, const void* __restrict__ res,
                 void* __restrict__ Cout, int M, int N, int K)
{
    __shared__ u16 As[128 * 32];
    __shared__ u16 Bs[64 * 32];
    const int t = threadIdx.x;
    const int w = t >> 6, l = t & 63;
    const int m0 = blockIdx.y * 128, n0 = blockIdx.x * 64;
    const int qk = l >> 4, col = l & 15;
    const int wm = (w & 1) * 64, wn = (w >> 1) * 32;
    const int sr = l >> 2, sq = l & 3;
    const int row = w * 16 + sr;
    const int gq = sq ^ ((row >> 1) & 3);
    const u16* Ap = A + (size_t)(m0 + row) * K + gq * 8;
    const u16* Bp = B + (size_t)(n0 + row) * K + gq * 8;
    u16* AsW = As + w * 16 * 32;
    u16* BsW = Bs + w * 16 * 32;
    const int mloc = wm + col, nloc = wn + col;
    const u16* aBase = As + mloc * 32 + (qk ^ ((mloc >> 1) & 3)) * 8;
    const u16* bBase = Bs + nloc * 32 + (qk ^ ((nloc >> 1) & 3)) * 8;
    floatx4 acc[4][2];
#pragma unroll
    for (int i = 0; i < 4; i++)
#pragma unroll
        for (int j = 0; j < 2; j++) acc[i][j] = (floatx4)0.f;
    for (int k0 = 0; k0 < K; k0 += 32) {
        __syncthreads();
        async16(Ap, AsW);
        async16(Ap + (size_t)64 * K, AsW + 64 * 32);
        async16(Bp, BsW);
        Ap += 32; Bp += 32;
        __syncthreads();
        short8 a[4], b[2];
#pragma unroll
        for (int i = 0; i < 4; i++) a[i] = *(const short8*)(aBase + i * 16 * 32);
#pragma unroll
        for (int j = 0; j < 2; j++) b[j] = *(const short8*)(bBase + j * 16 * 32);
#pragma unroll
        for (int i = 0; i < 4; i++)
#pragma unroll
            for (int j = 0; j < 2; j++)
                acc[i][j] = __builtin_amdgcn_mfma_f32_16x16x32_bf16(
                    a[i], b[j], acc[i][j], 0, 0, 0);
    }
#pragma unroll
    for (int j = 0; j < 2; j++) {
        const int n = n0 + wn + j * 16 + col;
        const float bn = bias[n];
#pragma unroll
        for (int i = 0; i < 4; i++) {
#pragma unroll
            for (int r = 0; r < 4; r++) {
                const int m = m0 + wm + i * 16 + qk * 4 + r;
                float v = acc[i][j][r] + bn;
                if (RES == 1) v += ((const float*)res)[(size_t)m * N + n];
                if (RES == 2) v += bu2f(((const u16*)res)[(size_t)m * N + n]);
                if (OMODE == 0) ((float*)Cout)[(size_t)m * N + n] = v;
                if (OMODE == 1) ((u16*)Cout)[(size_t)m * N + n] = f2bu(v);
            }
        }
    }
}

// =================== f16 MFMA fused sparse attention v7 ======================
// R4 counters: dur flat at 83us, occ pinned 39% at VGPR 44 -> NOT occupancy-
// bound. Per-block latency ~77k cy vs ~70 global loads => loads are nearly
// SERIALIZED (no MLP at 44 regs). v7 spends registers on load-in-flight:
//  (a) K-phase rotation depth 4 (kA/kB[4]): 8 loads outstanding; tail tiles
//      16,17 prefetched inside the main loop (latency hidden).
//  (b) V loads hoisted to Newton-start (vf[8] + vg[4] for the tail): ~1300cy
//      of Newton VALU covers their latency; PV rotates vf at depth 8.
//  All prefetch addresses statically in-bounds (rows < 2048, cols < S) ->
//  prefetch unconditional, guards remain on compute only, indices static.
//  launch_bounds(256,3): ~170-reg cap, zero spill risk (est. peak ~105).
__global__ __launch_bounds__(256, 3)
void attn_small(const u16* __restrict__ qb, const u16* __restrict__ kb,
                const u16* __restrict__ vT, const int* __restrict__ nkbuf,
                u16* __restrict__ att)
{
    const int nk = nkbuf[0];
    if (nk > 1152) return;              // big-path kernel handles this
    __shared__ u16 Plds[16 * 1024];     // 32 KB: scores, then P
    const int NS = (nk + 127) >> 7;     // active 128-key register slots (1..9)
    const int NT = (nk + 31) >> 5;      // active 32-key PV tiles (1..36)
    const int hh = blockIdx.x >> 7;
    const int q0 = (blockIdx.x & 127) * 16;
    const int t  = threadIdx.x;
    const int w  = __builtin_amdgcn_readfirstlane(t >> 6);   // wave id -> SGPR
    const int l  = t & 63;
    const int lg = l >> 4, lc = l & 15;

    // Q as B-operand: B[n=lc (q-row)][k=lg*8+j]
    const u16* qp = qb + (size_t)(q0 + lc) * D + hh * HD + lg * 8;
    const half8v bq0 = *(const half8v*)qp;
    const half8v bq1 = *(const half8v*)(qp + 32);
    const u16* kbase = kb + hh * HD + lg * 8;

    // ---- K prefetch prologue: tiles 0..3 (rows < 1024, always in-bounds) ----
    half8v kA[4], kB[4];
#pragma unroll
    for (int T = 0; T < 4; T++) {
        const u16* kp = kbase + (size_t)((4 * T + w) * 16 + lc) * D;
        kA[T] = *(const half8v*)kp;
        kB[T] = *(const half8v*)(kp + 32);
    }

    // ---- Phase A: FUSED QK^T + transpose-write, rotation depth 4 ----
    // lane: q-row = lc, keys = 16g + lg*4 + r; write b64 at row lc, swizzled.
#pragma unroll
    for (int T = 0; T < 16; T++) {
        const int g  = 4 * T + w;
        const int sl = T & 3;
        const half8v A0 = kA[sl], A1 = kB[sl];
        if (T + 4 < 18) {               // prefetch T+4 (incl. tail tiles 16,17)
            const u16* kp = kbase + (size_t)((4 * (T + 4) + w) * 16 + lc) * D;
            kA[sl] = *(const half8v*)kp;
            kB[sl] = *(const half8v*)(kp + 32);
        }
        if (g < 8 * NS) {               // wave-uniform compute guard
            floatx4 a = (floatx4)0.f;
            a = mfma_f16(A0, bq0, a);   // A = K !
            a = mfma_f16(A1, bq1, a);
            half4v scv;
            if ((g + 1) * 16 <= nk) {   // full tile: no per-key select
                half2v p01 = pkrtz(a[0] * 0.0625f, a[1] * 0.0625f);
                half2v p23 = pkrtz(a[2] * 0.0625f, a[3] * 0.0625f);
                scv = __builtin_shufflevector(p01, p23, 0, 1, 2, 3);
            } else {                    // boundary/garbage: keys >= nk -> -30000
                const int kb0 = g * 16 + lg * 4;
                half2v p01 = pkrtz(kb0 + 0 < nk ? a[0] * 0.0625f : -30000.f,
                                   kb0 + 1 < nk ? a[1] * 0.0625f : -30000.f);
                half2v p23 = pkrtz(kb0 + 2 < nk ? a[2] * 0.0625f : -30000.f,
                                   kb0 + 3 < nk ? a[3] * 0.0625f : -30000.f);
                scv = __builtin_shufflevector(p01, p23, 0, 1, 2, 3);
            }
            const int kl = g * 16 + lg * 4;
            const int b  = kl >> 3;
            const int p  = b ^ ((b >> 3) & 7) ^ (lc & 7);
            *(half4v*)&Plds[lc * 1024 + p * 8 + (lg & 1) * 4] = scv;
        }
    }
    __syncthreads();

    // ---- transpose-read: lane owns row R; slot s = keys [128s,128s+128),
    //      this lane's 8: 128s + lc*8 .. +7  (b = 16s + lc) ----
    const int R = 4 * w + lg;
    half8v xq[9];
#pragma unroll
    for (int s = 0; s < 8; s++) {
        if (s < NS) {
            const int b = 16 * s + lc;
            const int p = b ^ ((b >> 3) & 7) ^ (R & 7);
            xq[s] = *(const half8v*)&Plds[R * 1024 + p * 8];
        }
    }
    if (NS > 8) {                       // slot 8: keys [1024, 1152) via chunk
        __syncthreads();                // all reads of slot-0 region done
        // tail tiles 16,17 (g = 64+w, 68+w) using kA[0..1]/kB[0..1] prefetched
        // during the main loop -> latency already hidden
#pragma unroll
        for (int T = 16; T < 18; T++) {
            const int g = 4 * T + w;
            const half8v A0 = kA[T - 16], A1 = kB[T - 16];
            floatx4 a = (floatx4)0.f;
            a = mfma_f16(A0, bq0, a);
            a = mfma_f16(A1, bq1, a);
            half4v scv;
            const int kb0 = g * 16 + lg * 4;
            if ((g + 1) * 16 <= nk) {
                half2v p01 = pkrtz(a[0] * 0.0625f, a[1] * 0.0625f);
                half2v p23 = pkrtz(a[2] * 0.0625f, a[3] * 0.0625f);
                scv = __builtin_shufflevector(p01, p23, 0, 1, 2, 3);
            } else {
                half2v p01 = pkrtz(kb0 + 0 < nk ? a[0] * 0.0625f : -30000.f,
                                   kb0 + 1 < nk ? a[1] * 0.0625f : -30000.f);
                half2v p23 = pkrtz(kb0 + 2 < nk ? a[2] * 0.0625f : -30000.f,
                                   kb0 + 3 < nk ? a[3] * 0.0625f : -30000.f);
                scv = __builtin_shufflevector(p01, p23, 0, 1, 2, 3);
            }
            const int kl = kb0 - 1024;   // chunk-local
            const int b  = kl >> 3;
            const int p  = b ^ ((b >> 3) & 7) ^ (lc & 7);
            *(half4v*)&Plds[lc * 1024 + p * 8 + (lg & 1) * 4] = scv;
        }
        __syncthreads();
        {
            const int b = lc;           // chunk-local slot read (s=0 form)
            const int p = b ^ ((b >> 3) & 7) ^ (R & 7);
            xq[8] = *(const half8v*)&Plds[R * 1024 + p * 8];
        }
    }

    // ---- V prefetch: issue BEFORE Newton (V independent of tau); Newton's
    //      ~1300cy of VALU hides the L2/L3 latency. vf: PV tiles 0..7;
    //      vg: tail tiles 32..35 (cols < S, always in-bounds). ----
    const u16* vp = vT + (size_t)(hh * HD + w * 16 + lc) * S + lg * 8;
    half8v vf[8];
#pragma unroll
    for (int i = 0; i < 8; i++) vf[i] = *(const half8v*)(vp + i * 32);
    half8v vg[4];
    if (NS > 8) {
#pragma unroll
        for (int i = 0; i < 4; i++) vg[i] = *(const half8v*)(vp + 1024 + i * 32);
    }

    // ---- row max over active slots (in-lane + DPP 16-lane reduce) ----
    float tau;
    {
        half8v m8 = xq[0];              // slot 0 always active (nk >= 1)
#pragma unroll
        for (int i = 1; i < 9; i++)
            if (i < NS) m8 = __builtin_elementwise_max(m8, xq[i]);
        union { half8v v; half2v h[4]; } u; u.v = m8;
        half2v m2 = __builtin_elementwise_max(
            __builtin_elementwise_max(u.h[0], u.h[1]),
            __builtin_elementwise_max(u.h[2], u.h[3]));
        float mx = fmaxf((float)m2[0], (float)m2[1]);
        mx = rowmax16(mx);
        tau = mx - 1.0f;                // g(tau0) >= 1 -> monotone Newton
    }

    // ---- Newton, early-exit, ZERO barriers: g(tau) = sum relu(x-tau)^2 = 1 --
    const half2v one2 = {(_Float16)1.f, (_Float16)1.f};
    const float nact = (float)(8 * NS);
#pragma unroll 1
    for (int it = 0; it < 12; it++) {
        const _Float16 th = (_Float16)tau;
        const float tf = (float)th;      // exact f32 image of the f16 tau
        const half8v t8 = {th, th, th, th, th, th, th, th};
        float m1a = 0.f, m1b = 0.f, m2a = 0.f, m2b = 0.f;
#pragma unroll
        for (int i = 0; i < 9; i++) {
            if (i < NS) {
                union { half8v v; half2v h[4]; } u;
                u.v = __builtin_elementwise_max(xq[i], t8);   // m = max(x, tau)
                m1a = fdot2f(u.h[0], one2, m1a);
                m2a = fdot2f(u.h[0], u.h[0], m2a);
                m1b = fdot2f(u.h[1], one2, m1b);
                m2b = fdot2f(u.h[1], u.h[1], m2b);
                m1a = fdot2f(u.h[2], one2, m1a);
                m2a = fdot2f(u.h[2], u.h[2], m2a);
                m1b = fdot2f(u.h[3], one2, m1b);
                m2b = fdot2f(u.h[3], u.h[3], m2b);
            }
        }
        const float M1 = m1a + m1b, M2 = m2a + m2b;
        float s1 = fmaf(-nact, tf, M1);
        float s2 = fmaf(tf, fmaf(nact, tf, -2.f * M1), M2);
        s1 = rowsum16(s1);
        s2 = rowsum16(s2);
        const float delta = (s2 - 1.0f) / (2.0f * fmaxf(s1, 1e-4f));
        tau += delta;
        if (__all(fabsf(delta) < 2.5e-4f)) break;
    }

    // ---- P = relu(x-tau)^2 in-place (same self-owned slots) + PV ----
    const _Float16 th = (_Float16)tau;
    const half8v t8 = {th, th, th, th, th, th, th, th};
    const half8v z8 = (half8v)(_Float16)0.f;
    floatx4 oa0 = (floatx4)0.f, oa1 = (floatx4)0.f;
    floatx4 oa2 = (floatx4)0.f, oa3 = (floatx4)0.f;
#pragma unroll
    for (int s = 0; s < 8; s++) {
        if (s < NS) {
            half8v dp = __builtin_elementwise_max(xq[s] - t8, z8);
            const int b = 16 * s + lc;
            const int p = b ^ ((b >> 3) & 7) ^ (R & 7);
            *(half8v*)&Plds[R * 1024 + p * 8] = dp * dp;
        }
    }
    __syncthreads();
    __builtin_amdgcn_s_setprio(1);
#pragma unroll
    for (int kt = 0; kt < 32; kt++) {
        if (kt < NT) {
            const int sl = kt & 7;
            const half8v bf = vf[sl];                          // B: V^T[d]
            if (kt + 8 < 32)                                   // rotate depth 8
                vf[sl] = *(const half8v*)(vp + (kt + 8) * 32);
            const int b = kt * 4 + lg;
            const int p = b ^ ((b >> 3) & 7) ^ (lc & 7);
            half8v af = *(const half8v*)&Plds[lc * 1024 + p * 8];  // A: P[row=lc]
            if ((kt & 3) == 0)      oa0 = mfma_f16(af, bf, oa0);
            else if ((kt & 3) == 1) oa1 = mfma_f16(af, bf, oa1);
            else if ((kt & 3) == 2) oa2 = mfma_f16(af, bf, oa2);
            else                    oa3 = mfma_f16(af, bf, oa3);
        }
    }
    __builtin_amdgcn_s_setprio(0);
    if (NS > 8) {                       // slot-8 P via chunk, PV tiles 32..35
        __syncthreads();                // PV reads of slot-0 region done
        {
            half8v dp = __builtin_elementwise_max(xq[8] - t8, z8);
            const int b = lc;
            const int p = b ^ ((b >> 3) & 7) ^ (R & 7);
            *(half8v*)&Plds[R * 1024 + p * 8] = dp * dp;
        }
        __syncthreads();
#pragma unroll
        for (int kt2 = 0; kt2 < 4; kt2++) {
            if (32 + kt2 < NT) {
                const int b = kt2 * 4 + lg;
                const int p = b ^ ((b >> 3) & 7) ^ (lc & 7);
                half8v af = *(const half8v*)&Plds[lc * 1024 + p * 8];
                if ((kt2 & 3) == 0)      oa0 = mfma_f16(af, vg[kt2], oa0);
                else if ((kt2 & 3) == 1) oa1 = mfma_f16(af, vg[kt2], oa1);
                else if ((kt2 & 3) == 2) oa2 = mfma_f16(af, vg[kt2], oa2);
                else                     oa3 = mfma_f16(af, vg[kt2], oa3);
            }
        }
    }
    const floatx4 oacc = (oa0 + oa1) + (oa2 + oa3);
#pragma unroll
    for (int r = 0; r < 4; r++)
        att[(size_t)(q0 + lg * 4 + r) * D + hh * HD + w * 16 + lc] = f2bu(oacc[r]);
}

// ---- big-nk fallback (v5 structure, nk > 1152; P ~ 2e-4 for this data) ------
__global__ __launch_bounds__(256, 5)
void attn_f16(const u16* __restrict__ qb, const u16* __restrict__ kb,
              const u16* __restrict__ vT, const int* __restrict__ nkbuf,
              u16* __restrict__ att)
{
    const int nk = nkbuf[0];
    if (nk <= 1152) return;             // small-path kernel handled it
    __shared__ u16 Plds[16 * 1024];
    const int NS = (nk + 127) >> 7;
    const int NT = (nk + 31) >> 5;
    const int hh = blockIdx.x >> 7;
    const int q0 = (blockIdx.x & 127) * 16;
    const int t  = threadIdx.x;
    const int w  = __builtin_amdgcn_readfirstlane(t >> 6);
    const int l  = t & 63;
    const int lg = l >> 4, lc = l & 15;
    const _Float16 NEG = (_Float16)(-30000.f);

    const u16* qp = qb + (size_t)(q0 + lc) * D + hh * HD + lg * 8;
    const half8v bq0 = *(const half8v*)qp;
    const half8v bq1 = *(const half8v*)(qp + 32);

    half4v sc[32];
    {
        const u16* kbase = kb + hh * HD + lg * 8;
        __builtin_amdgcn_s_setprio(1);
#pragma unroll
        for (int T = 0; T < 32; T++) {
            const int g = 4 * T + w;
            if (g * 16 < nk) {
                const u16* kp = kbase + (size_t)(g * 16 + lc) * D;
                floatx4 a = (floatx4)0.f;
                a = mfma_f16(*(const half8v*)kp,        bq0, a);
                a = mfma_f16(*(const half8v*)(kp + 32), bq1, a);
                const int kb0 = g * 16 + lg * 4;
                half2v p01 = pkrtz(kb0 + 0 < nk ? a[0] * 0.0625f : -30000.f,
                                   kb0 + 1 < nk ? a[1] * 0.0625f : -30000.f);
                half2v p23 = pkrtz(kb0 + 2 < nk ? a[2] * 0.0625f : -30000.f,
                                   kb0 + 3 < nk ? a[3] * 0.0625f : -30000.f);
                sc[T] = __builtin_shufflevector(p01, p23, 0, 1, 2, 3);
            } else {
                sc[T] = (half4v){NEG, NEG, NEG, NEG};
            }
        }
        __builtin_amdgcn_s_setprio(0);
    }

    const int R = 4 * w + lg;
    half8v xq[16];
    {
#pragma unroll
        for (int T = 0; T < 16; T++) {
            const int g  = 4 * T + w;
            const int kl = g * 16 + lg * 4;
            const int b  = kl >> 3;
            const int p  = b ^ ((b >> 3) & 7) ^ (lc & 7);
            *(half4v*)&Plds[lc * 1024 + p * 8 + (lg & 1) * 4] = sc[T];
        }
        __syncthreads();
#pragma unroll
        for (int s = 0; s < 8; s++) {
            if (s < NS) {
                const int b = 16 * s + lc;
                const int p = b ^ ((b >> 3) & 7) ^ (R & 7);
                xq[s] = *(const half8v*)&Plds[R * 1024 + p * 8];
            }
        }
        __syncthreads();
#pragma unroll
        for (int T = 16; T < 32; T++) {
            const int g  = 4 * T + w;
            const int kl = g * 16 + lg * 4 - 1024;
            const int b  = kl >> 3;
            const int p  = b ^ ((b >> 3) & 7) ^ (lc & 7);
            *(half4v*)&Plds[lc * 1024 + p * 8 + (lg & 1) * 4] = sc[T];
        }
        __syncthreads();
#pragma unroll
        for (int s = 0; s < 8; s++) {
            const int j = 8 + s;
            if (j < NS) {
                const int b = 16 * s + lc;
                const int p = b ^ ((b >> 3) & 7) ^ (R & 7);
                xq[j] = *(const half8v*)&Plds[R * 1024 + p * 8];
            }
        }
    }

    float tau;
    {
        half8v m8 = xq[0];
#pragma unroll
        for (int i = 1; i < 16; i++)
            if (i < NS) m8 = __builtin_elementwise_max(m8, xq[i]);
        union { half8v v; half2v h[4]; } u; u.v = m8;
        half2v m2 = __builtin_elementwise_max(
            __builtin_elementwise_max(u.h[0], u.h[1]),
            __builtin_elementwise_max(u.h[2], u.h[3]));
        float mx = fmaxf((float)m2[0], (float)m2[1]);
        mx = rowmax16(mx);
        tau = mx - 1.0f;
    }

    const half2v one2 = {(_Float16)1.f, (_Float16)1.f};
    const float nact = (float)(8 * NS);
#pragma unroll 1
    for (int it = 0; it < 12; it++) {
        const _Float16 th = (_Float16)tau;
        const float tf = (float)th;
        const half8v t8 = {th, th, th, th, th, th, th, th};
        float m1a = 0.f, m1b = 0.f, m2a = 0.f, m2b = 0.f;
#pragma unroll
        for (int i = 0; i < 16; i++) {
            if (i < NS) {
                union { half8v v; half2v h[4]; } u;
                u.v = __builtin_elementwise_max(xq[i], t8);
                m1a = fdot2f(u.h[0], one2, m1a);
                m2a = fdot2f(u.h[0], u.h[0], m2a);
                m1b = fdot2f(u.h[1], one2, m1b);
                m2b = fdot2f(u.h[1], u.h[1], m2b);
                m1a = fdot2f(u.h[2], one2, m1a);
                m2a = fdot2f(u.h[2], u.h[2], m2a);
                m1b = fdot2f(u.h[3], one2, m1b);
                m2b = fdot2f(u.h[3], u.h[3], m2b);
            }
        }
        const float M1 = m1a + m1b, M2 = m2a + m2b;
        float s1 = fmaf(-nact, tf, M1);
        float s2 = fmaf(tf, fmaf(nact, tf, -2.f * M1), M2);
        s1 = rowsum16(s1);
        s2 = rowsum16(s2);
        const float delta = (s2 - 1.0f) / (2.0f * fmaxf(s1, 1e-4f));
        tau += delta;
        if (__all(fabsf(delta) < 2.5e-4f)) break;
    }

    const _Float16 th = (_Float16)tau;
    const half8v t8 = {th, th, th, th, th, th, th, th};
    const half8v z8 = (half8v)(_Float16)0.f;
    floatx4 oa0 = (floatx4)0.f, oa1 = (floatx4)0.f;
    floatx4 oa2 = (floatx4)0.f, oa3 = (floatx4)0.f;
    const u16* vp = vT + (size_t)(hh * HD + w * 16 + lc) * S + lg * 8;
#pragma unroll
    for (int s = 0; s < 8; s++) {
        if (s < NS) {
            half8v dp = __builtin_elementwise_max(xq[s] - t8, z8);
            const int b = 16 * s + lc;
            const int p = b ^ ((b >> 3) & 7) ^ (R & 7);
            *(half8v*)&Plds[R * 1024 + p * 8] = dp * dp;
        }
    }
    __syncthreads();
    __builtin_amdgcn_s_setprio(1);
#pragma unroll
    for (int kt = 0; kt < 32; kt++) {
        if (kt < NT) {
            const int b = kt * 4 + lg;
            const int p = b ^ ((b >> 3) & 7) ^ (lc & 7);
            half8v af = *(const half8v*)&Plds[lc * 1024 + p * 8];
            half8v bf = *(const half8v*)(vp + kt * 32);
            if ((kt & 3) == 0)      oa0 = mfma_f16(af, bf, oa0);
            else if ((kt & 3) == 1) oa1 = mfma_f16(af, bf, oa1);
            else if ((kt & 3) == 2) oa2 = mfma_f16(af, bf, oa2);
            else                    oa3 = mfma_f16(af, bf, oa3);
        }
    }
    __builtin_amdgcn_s_setprio(0);
    {
        __syncthreads();
#pragma unroll
        for (int s = 0; s < 8; s++) {
            const int j = 8 + s;
            if (j < NS) {
                half8v dp = __builtin_elementwise_max(xq[j] - t8, z8);
                const int b = 16 * s + lc;
                const int p = b ^ ((b >> 3) & 7) ^ (R & 7);
                *(half8v*)&Plds[R * 1024 + p * 8] = dp * dp;
            }
        }
        __syncthreads();
        const u16* vph = vp + 1024;
        __builtin_amdgcn_s_setprio(1);
#pragma unroll
        for (int kt = 0; kt < 32; kt++) {
            if (32 + kt < NT) {
                const int b = kt * 4 + lg;
                const int p = b ^ ((b >> 3) & 7) ^ (lc & 7);
                half8v af = *(const half8v*)&Plds[lc * 1024 + p * 8];
                half8v bf = *(const half8v*)(vph + kt * 32);
                if ((kt & 3) == 0)      oa0 = mfma_f16(af, bf, oa0);
                else if ((kt & 3) == 1) oa1 = mfma_f16(af, bf, oa1);
                else if ((kt & 3) == 2) oa2 = mfma_f16(af, bf, oa2);
                else                    oa3 = mfma_f16(af, bf, oa3);
            }
        }
        __builtin_amdgcn_s_setprio(0);
    }
    const floatx4 oacc = (oa0 + oa1) + (oa2 + oa3);
#pragma unroll
    for (int r = 0; r < 4; r++)
        att[(size_t)(q0 + lg * 4 + r) * D + hh * HD + w * 16 + lc] = f2bu(oacc[r]);
}

// ---------------- host side ---------------------------------------------------
extern "C" void kernel_launch(void* const* d_in, const int* in_sizes, int n_in,
                              void* d_out, int out_size, void* d_ws, size_t ws_size,
                              hipStream_t stream)
{
    const float* inp  = (const float*)d_in[0];
    const int*   mask = (const int*)d_in[1];
    const float* wq   = (const float*)d_in[2];
    const float* bq   = (const float*)d_in[3];
    const float* wk   = (const float*)d_in[4];
    const float* bk   = (const float*)d_in[5];
    const float* wv   = (const float*)d_in[6];
    const float* bv   = (const float*)d_in[7];
    const float* wo   = (const float*)d_in[8];
    const float* bo   = (const float*)d_in[9];
    const float* ln1a = (const float*)d_in[10];
    const float* ln1b = (const float*)d_in[11];
    const float* w1   = (const float*)d_in[12];
    const float* b1   = (const float*)d_in[13];
    const float* w2   = (const float*)d_in[14];
    const float* b2   = (const float*)d_in[15];
    const float* ln2a = (const float*)d_in[16];
    const float* ln2b = (const float*)d_in[17];

    const size_t MB = 1u << 20;
    char* w = (char*)d_ws;
    // 32 MB overlay (16-bit bufs unless noted):
    //  [0,8):  wqkvb(6MB) -> w1b (after QKV) -> w2b (after FFN1)
    //  [8,12): x1 -> att -> x2   (bf16)
    //  [12,16): qb_ (f16) -> yb (bf16)
    //  [16,20): kb_ (f16)  \
    //  [20,24): vTb (f16)   > dead after attn -> hb [16,32)
    //  [24,26): wob (bf16) /  (dead after WO, before FFN1 writes hb)
    //  [26, 26MB+8KB+4): newpos int[2048] + nk  (dead before FFN1 writes hb)
    u16* wqkvb = (u16*)(w + 0 * MB);
    u16* w1b   = (u16*)(w + 0 * MB);
    u16* w2b   = (u16*)(w + 0 * MB);
    u16* x1    = (u16*)(w + 8 * MB);
    u16* att   = x1;
    u16* x2    = x1;
    u16* qb_   = (u16*)(w + 12 * MB);
    u16* yb    = (u16*)(w + 12 * MB);
    u16* kb_   = (u16*)(w + 16 * MB);
    u16* vTb   = (u16*)(w + 20 * MB);
    u16* wob   = (u16*)(w + 24 * MB);
    u16* hb    = (u16*)(w + 16 * MB);
    int* np    = (int*)(w + 26 * MB);
    int* nkbuf = np + 2048;
    float* outF = (float*)d_out;

    // -1. key-compaction scan (mask only)
    scan_mask_kernel<<<1, 256, 0, stream>>>(mask, np, nkbuf);
    // 0. weight conversions: QKV concat + WO
    cvt_kernel<<<1024, 256, 0, stream>>>(wq, wqkvb,                   (D * D) / 4);
    cvt_kernel<<<1024, 256, 0, stream>>>(wk, wqkvb + 1024 * 1024,     (D * D) / 4);
    cvt_kernel<<<1024, 256, 0, stream>>>(wv, wqkvb + 2 * 1024 * 1024, (D * D) / 4);
    cvt_kernel<<<1024, 256, 0, stream>>>(wo, wob, (D * D) / 4);
    // 1. LN1 -> bf16
    ln_kernel<float><<<S, 256, 0, stream>>>(inp, ln1a, ln1b, x1);
    // 2. fused QKV projection -> f16 Q [S,D]; K [S,D], V^T [D,S] permuted
    gemm_qkv<<<dim3(3 * D / 128, S / 128), 256, 0, stream>>>(
        x1, wqkvb, bq, bk, bv, np, qb_, kb_, vTb);
    // 3. convert w1 (wqkvb dead)
    cvt_kernel<<<4096, 256, 0, stream>>>(w1, w1b, (DFF * D) / 4);
    // 4. f16 MFMA fused entmax attention (compacted keys) -> att bf16
    //    dual-dispatch: small (nk <= 1152, MLP-prefetch) or big fallback
    attn_small<<<NH * (S / 16), 256, 0, stream>>>(qb_, kb_, vTb, nkbuf, att);
    attn_f16<<<NH * (S / 16), 256, 0, stream>>>(qb_, kb_, vTb, nkbuf, att);
    // 5. WO projection + residual(inp fp32) -> yb bf16  (256 blocks)
    gemm_mfma64<1, 1><<<dim3(D / 64, S / 128), 256, 0, stream>>>(
        att, wob, bo, inp, yb, S, D, D);
    // 6. LN2 -> x2 (att dead)
    ln_kernel<u16><<<S, 256, 0, stream>>>(yb, ln2a, ln2b, x2);
    // 7. FFN1 (+ReLU) -> hb bf16 (kb_/vTb/wob/np dead)
    gemm_mfma<1, true, 0><<<dim3(DFF / 128, S / 128), 256, 0, stream>>>(
        x2, w1b, b1, nullptr, hb, S, DFF, D);
    // 8. convert w2 (w1b dead)
    cvt_kernel<<<4096, 256, 0, stream>>>(w2, w2b, (DFF * D) / 4);
    // 9. FFN2 + residual(yb bf16) -> fp32 out  (256 blocks)
    gemm_mfma64<0, 2><<<dim3(D / 64, S / 128), 256, 0, stream>>>(
        hb, w2b, b2, yb, outF, S, D, DFF);
}

// Round 6
// 340.452 us; speedup vs baseline: 1.0568x; 1.0568x over previous
//
#include <hip/hip_runtime.h>
#include <hip/hip_bf16.h>

// Problem dims (fixed by setup_inputs)
#define S   2048
#define D   1024
#define DFF 4096
#define NH  16
#define HD  64

typedef unsigned short u16;
typedef unsigned int   u32;
typedef __attribute__((ext_vector_type(8))) short      short8;  // 8 bf16
typedef __attribute__((ext_vector_type(4))) float      floatx4; // MFMA C/D
typedef __attribute__((ext_vector_type(2))) _Float16   half2v;
typedef __attribute__((ext_vector_type(4))) _Float16   half4v;
typedef __attribute__((ext_vector_type(8))) _Float16   half8v;

__device__ __forceinline__ float bu2f(u16 u) {
    union { u32 i; float f; } x; x.i = ((u32)u) << 16; return x.f;
}
__device__ __forceinline__ u16 f2bu(float f) {
    __hip_bfloat16 h = __float2bfloat16(f);
    return *(u16*)&h;
}
__device__ __forceinline__ u16 f2h(float f) {
    _Float16 h = (_Float16)f; return *(u16*)&h;
}
__device__ __forceinline__ float ldf(const float* p) { return *p; }
__device__ __forceinline__ float ldf(const u16* p)   { return bu2f(*p); }

// cvt_pkrtz returns __fp16x2; bit-cast to our _Float16x2 (same 32-bit reg)
__device__ __forceinline__ half2v pkrtz(float a, float b) {
    auto v = __builtin_amdgcn_cvt_pkrtz(a, b);
    union { decltype(v) i; half2v o; } u; u.i = v; return u.o;
}

__device__ __forceinline__ floatx4 mfma_f16(half8v a, half8v b, floatx4 c) {
    return __builtin_amdgcn_mfma_f32_16x16x32_f16(a, b, c, 0, 0, 0);
}
__device__ __forceinline__ float fdot2f(half2v a, half2v b, float c) {
#if __has_builtin(__builtin_amdgcn_fdot2)
    return __builtin_amdgcn_fdot2(a, b, c, false);
#else
    return c + (float)a[0] * (float)b[0] + (float)a[1] * (float)b[1];
#endif
}

// ---- DPP 16-lane row reductions (VALU-speed, replaces ds_swizzle chains) ----
template <int K>
__device__ __forceinline__ float ror16f(float v) {
    int s = __builtin_bit_cast(int, v);
    int r = __builtin_amdgcn_update_dpp(s, s, 0x120 | K, 0xF, 0xF, false);
    return __builtin_bit_cast(float, r);
}
__device__ __forceinline__ float rowsum16(float v) {
    v += ror16f<1>(v);
    v += ror16f<2>(v);
    v += ror16f<4>(v);
    v += ror16f<8>(v);
    return v;
}
__device__ __forceinline__ float rowmax16(float v) {
    v = fmaxf(v, ror16f<1>(v));
    v = fmaxf(v, ror16f<2>(v));
    v = fmaxf(v, ror16f<4>(v));
    v = fmaxf(v, ror16f<8>(v));
    return v;
}

// async global->LDS, 16B per lane, lands at ldsbase + lane*16
__device__ __forceinline__ void async16(const void* g, void* l) {
    __builtin_amdgcn_global_load_lds(
        (const __attribute__((address_space(1))) u32*)g,
        (__attribute__((address_space(3))) u32*)l, 16, 0, 0);
}

// pipeline primitives (counted vmcnt, raw barrier; rule #18: sched_barrier
// after every inline-asm wait)
#define WAITV(N) asm volatile("s_waitcnt vmcnt(" N ")" ::: "memory")
#define WAITL()  asm volatile("s_waitcnt lgkmcnt(0)" ::: "memory")
#define SBAR()   __builtin_amdgcn_s_barrier()
#define SCHED0() __builtin_amdgcn_sched_barrier(0)

// ---------------- fp32 -> bf16 bulk convert (weights) ------------------------
__global__ __launch_bounds__(256)
void cvt_kernel(const float* __restrict__ in, u16* __restrict__ out, int n4)
{
    int i = blockIdx.x * 256 + threadIdx.x;
    if (i < n4) {
        float4 v = ((const float4*)in)[i];
        ushort4 s;
        s.x = f2bu(v.x); s.y = f2bu(v.y); s.z = f2bu(v.z); s.w = f2bu(v.w);
        ((ushort4*)out)[i] = s;
    }
}

// ---------------- key-compaction scan: newpos[] + nk from mask ---------------
// Unmasked keys -> [0, nk) (order-preserving), masked -> [nk, 2048).
// Attention is permutation-invariant over keys, and masked keys' P == 0.
__global__ __launch_bounds__(256)
void scan_mask_kernel(const int* __restrict__ mask, int* __restrict__ newpos,
                      int* __restrict__ nkbuf)
{
    __shared__ int ps[256];
    const int t = threadIdx.x;
    int loc[8];
    int s = 0;
#pragma unroll
    for (int j = 0; j < 8; j++) {
        loc[j] = s;
        s += (mask[t * 8 + j] != 0);
    }
    ps[t] = s;
    __syncthreads();
    for (int off = 1; off < 256; off <<= 1) {
        int v = (t >= off) ? ps[t - off] : 0;
        __syncthreads();
        ps[t] += v;
        __syncthreads();
    }
    const int total = ps[255];                 // nk
    const int base = t ? ps[t - 1] : 0;        // unmasked count before this chunk
#pragma unroll
    for (int j = 0; j < 8; j++) {
        const int gi = t * 8 + j;
        const int up = base + loc[j];          // unmasked rank
        newpos[gi] = mask[gi] ? up : (total + gi - up);
    }
    if (t == 0) nkbuf[0] = total;
}

// ---------------- LayerNorm: one block per row, D=1024, 256 threads ----------
template <typename T>
__global__ __launch_bounds__(256, 4)
void ln_kernel(const T* __restrict__ in, const float* __restrict__ ga,
               const float* __restrict__ gb, u16* __restrict__ out)
{
    const int row = blockIdx.x;
    const int t = threadIdx.x;
    const T* x = in + (size_t)row * D;
    float v[4];
    float s = 0.f, ss = 0.f;
#pragma unroll
    for (int j = 0; j < 4; j++) {
        float val = ldf(x + t + 256 * j);
        v[j] = val; s += val; ss = fmaf(val, val, ss);
    }
#pragma unroll
    for (int off = 32; off >= 1; off >>= 1) {
        s  += __shfl_down(s,  off, 64);
        ss += __shfl_down(ss, off, 64);
    }
    __shared__ float red[10];
    const int wave = t >> 6, lane = t & 63;
    if (lane == 0) { red[wave] = s; red[4 + wave] = ss; }
    __syncthreads();
    if (t == 0) {
        float S1 = red[0] + red[1] + red[2] + red[3];
        float S2 = red[4] + red[5] + red[6] + red[7];
        float mu = S1 / (float)D;
        float var = (S2 - (float)D * mu * mu) / (float)(D - 1);  // ddof=1
        float sig = sqrtf(fmaxf(var, 0.f)) + 1e-6f;              // eps on sigma
        red[8] = mu; red[9] = 1.f / sig;
    }
    __syncthreads();
    const float mu = red[8], rs = red[9];
#pragma unroll
    for (int j = 0; j < 4; j++) {
        int c = t + 256 * j;
        out[(size_t)row * D + c] = f2bu((v[j] - mu) * rs * ga[c] + gb[c]);
    }
}

// ======================= MFMA GEMM core (128x128 tile) =======================
// v8: 3-buffer, depth-2 global_load_lds pipeline (T3+T4 minimum form).
// Invariant entering iter t: stage t resident+certified; t+1, t+2 in flight.
// Per iter: ds_read buf[t%3] -> lgkm(0)+SBAR (buffer free) -> stage t+3 into
// the SAME buffer -> MFMA -> vmcnt(8) counted (t+1 landed) + SBAR.
// Never vmcnt(0) in the main loop; tail peels immediates 4 -> 0.
#define GEMM_CORE(A_, B_, K_)                                                   \
    __shared__ u16 As[3 * 128 * 32];                                            \
    __shared__ u16 Bs[3 * 128 * 32];                                            \
    const int t = threadIdx.x;                                                  \
    const int w = t >> 6, l = t & 63;                                           \
    const int m0 = blockIdx.y * 128, n0 = blockIdx.x * 128;                     \
    const int qk = l >> 4, col = l & 15;                                        \
    const int wm = (w & 1) * 64, wn = (w >> 1) * 64;                            \
    const int sr  = l >> 2;                                                     \
    const int sq  = l & 3;                                                      \
    const int row = w * 16 + sr;                                                \
    const int gq  = sq ^ ((row >> 1) & 3);                                      \
    const u16* Ap = A_ + (size_t)(m0 + row) * K_ + gq * 8;                      \
    const u16* Bp = B_ + (size_t)(n0 + row) * K_ + gq * 8;                      \
    u16* AsW = As + w * 16 * 32;                                                \
    u16* BsW = Bs + w * 16 * 32;                                                \
    const int mloc = wm + col, nloc = wn + col;                                 \
    const int aoff = mloc * 32 + (qk ^ ((mloc >> 1) & 3)) * 8;                  \
    const int boff = nloc * 32 + (qk ^ ((nloc >> 1) & 3)) * 8;                  \
    floatx4 acc[4][4];                                                          \
    _Pragma("unroll")                                                           \
    for (int i = 0; i < 4; i++)                                                 \
        _Pragma("unroll")                                                       \
        for (int j = 0; j < 4; j++) acc[i][j] = (floatx4)0.f;                   \
    const int NT_ = K_ / 32;                                                    \
    _Pragma("unroll")                                                           \
    for (int s = 0; s < 3; s++) {                                               \
        async16(Ap,                   AsW + s * 4096);                          \
        async16(Ap + (size_t)64 * K_, AsW + s * 4096 + 64 * 32);                \
        async16(Bp,                   BsW + s * 4096);                          \
        async16(Bp + (size_t)64 * K_, BsW + s * 4096 + 64 * 32);                \
        Ap += 32; Bp += 32;                                                     \
    }                                                                           \
    WAITV("8"); SCHED0(); SBAR();                                               \
    int cur = 0;                                                                \
    for (int t0 = 0; t0 + 3 < NT_; ++t0) {                                      \
        short8 a[4], b[4];                                                      \
        const u16* aB = As + cur * 4096 + aoff;                                 \
        const u16* bB = Bs + cur * 4096 + boff;                                 \
        _Pragma("unroll")                                                       \
        for (int i = 0; i < 4; i++) a[i] = *(const short8*)(aB + i * 16 * 32);  \
        _Pragma("unroll")                                                       \
        for (int j = 0; j < 4; j++) b[j] = *(const short8*)(bB + j * 16 * 32);  \
        WAITL(); SCHED0(); SBAR();                                              \
        async16(Ap,                   AsW + cur * 4096);                        \
        async16(Ap + (size_t)64 * K_, AsW + cur * 4096 + 64 * 32);              \
        async16(Bp,                   BsW + cur * 4096);                        \
        async16(Bp + (size_t)64 * K_, BsW + cur * 4096 + 64 * 32);              \
        Ap += 32; Bp += 32;                                                     \
        _Pragma("unroll")                                                       \
        for (int i = 0; i < 4; i++)                                             \
            _Pragma("unroll")                                                   \
            for (int j = 0; j < 4; j++)                                         \
                acc[i][j] = __builtin_amdgcn_mfma_f32_16x16x32_bf16(            \
                    a[i], b[j], acc[i][j], 0, 0, 0);                            \
        WAITV("8"); SCHED0(); SBAR();                                           \
        cur = cur + 1; if (cur == 3) cur = 0;                                   \
    }                                                                           \
    _Pragma("unroll")                                                           \
    for (int tail = 0; tail < 3; tail++) {                                      \
        short8 a[4], b[4];                                                      \
        const u16* aB = As + cur * 4096 + aoff;                                 \
        const u16* bB = Bs + cur * 4096 + boff;                                 \
        _Pragma("unroll")                                                       \
        for (int i = 0; i < 4; i++) a[i] = *(const short8*)(aB + i * 16 * 32);  \
        _Pragma("unroll")                                                       \
        for (int j = 0; j < 4; j++) b[j] = *(const short8*)(bB + j * 16 * 32);  \
        _Pragma("unroll")                                                       \
        for (int i = 0; i < 4; i++)                                             \
            _Pragma("unroll")                                                   \
            for (int j = 0; j < 4; j++)                                         \
                acc[i][j] = __builtin_amdgcn_mfma_f32_16x16x32_bf16(            \
                    a[i], b[j], acc[i][j], 0, 0, 0);                            \
        if (tail == 0) { WAITV("4"); SCHED0(); SBAR(); }                        \
        if (tail == 1) { WAITV("0"); SCHED0(); SBAR(); }                        \
        cur = cur + 1; if (cur == 3) cur = 0;                                   \
    }

// ---- generic GEMM 128x128 (+bias/relu/res), OMODE 0 f32 / 1 bf16 ------------
template <int OMODE, bool RELU, int RES>
__global__ __launch_bounds__(256, 2)
void gemm_mfma(const u16* __restrict__ A, const u16* __restrict__ B,
               const float* __restrict__ bias, const void* __restrict__ res,
               void* __restrict__ Cout, int M, int N, int K)
{
    GEMM_CORE(A, B, K)
#pragma unroll
    for (int j = 0; j < 4; j++) {
        const int n = n0 + wn + j * 16 + col;
        const float bn = bias[n];
#pragma unroll
        for (int i = 0; i < 4; i++) {
#pragma unroll
            for (int r = 0; r < 4; r++) {
                const int m = m0 + wm + i * 16 + qk * 4 + r;
                float v = acc[i][j][r] + bn;
                if (RELU) v = fmaxf(v, 0.f);
                if (RES == 1) v += ((const float*)res)[(size_t)m * N + n];
                if (RES == 2) v += bu2f(((const u16*)res)[(size_t)m * N + n]);
                if (OMODE == 0) ((float*)Cout)[(size_t)m * N + n] = v;
                if (OMODE == 1) ((u16*)Cout)[(size_t)m * N + n] = f2bu(v);
            }
        }
    }
}

// ---- fused QKV GEMM (128x128): f16 Q [S,D]; K,V^T written PERMUTED by np ----
__global__ __launch_bounds__(256, 2)
void gemm_qkv(const u16* __restrict__ A, const u16* __restrict__ B,
              const float* __restrict__ bq, const float* __restrict__ bk,
              const float* __restrict__ bv, const int* __restrict__ np,
              u16* __restrict__ outQ, u16* __restrict__ outK,
              u16* __restrict__ outVT)
{
    const int K = D;
    GEMM_CORE(A, B, K)
    const int seg   = n0 >> 10;
    const int nbase = n0 & 1023;
    const float* bs = (seg == 0) ? bq : (seg == 1) ? bk : bv;
    int npm[4][4];
    if (seg != 0) {
#pragma unroll
        for (int i = 0; i < 4; i++)
#pragma unroll
            for (int r = 0; r < 4; r++)
                npm[i][r] = np[m0 + wm + i * 16 + qk * 4 + r];
    }
#pragma unroll
    for (int j = 0; j < 4; j++) {
        const int nl = nbase + wn + j * 16 + col;
        const float bn = bs[nl];
#pragma unroll
        for (int i = 0; i < 4; i++) {
#pragma unroll
            for (int r = 0; r < 4; r++) {
                const int m = m0 + wm + i * 16 + qk * 4 + r;
                float v = acc[i][j][r] + bn;
                if (seg == 0)      outQ [(size_t)m * D + nl]          = f2h(v);
                else if (seg == 1) outK [(size_t)npm[i][r] * D + nl]  = f2h(v);
                else               outVT[(size_t)nl * S + npm[i][r]]  = f2h(v);
            }
        }
    }
}

// ---- 128x64-tile GEMM, same 3-buffer depth-2 pipeline (WO, FFN2) ------------
template <int OMODE, int RES>
__global__ __launch_bounds__(256, 2)
void gemm_mfma64(const u16* __restrict__ A, const u16* __restrict__ B,
                 const float* __restrict__ bias, const void* __restrict__ res,
                 void* __restrict__ Cout, int M, int N, int K)
{
    __shared__ u16 As[3 * 128 * 32];
    __shared__ u16 Bs[3 * 64 * 32];
    const int t = threadIdx.x;
    const int w = t >> 6, l = t & 63;
    const int m0 = blockIdx.y * 128, n0 = blockIdx.x * 64;
    const int qk = l >> 4, col = l & 15;
    const int wm = (w & 1) * 64, wn = (w >> 1) * 32;
    const int sr = l >> 2, sq = l & 3;
    const int row = w * 16 + sr;
    const int gq = sq ^ ((row >> 1) & 3);
    const u16* Ap = A + (size_t)(m0 + row) * K + gq * 8;
    const u16* Bp = B + (size_t)(n0 + row) * K + gq * 8;
    u16* AsW = As + w * 16 * 32;
    u16* BsW = Bs + w * 16 * 32;
    const int mloc = wm + col, nloc = wn + col;
    const int aoff = mloc * 32 + (qk ^ ((mloc >> 1) & 3)) * 8;
    const int boff = nloc * 32 + (qk ^ ((nloc >> 1) & 3)) * 8;
    floatx4 acc[4][2];
#pragma unroll
    for (int i = 0; i < 4; i++)
#pragma unroll
        for (int j = 0; j < 2; j++) acc[i][j] = (floatx4)0.f;
    const int NT_ = K / 32;
#pragma unroll
    for (int s = 0; s < 3; s++) {
        async16(Ap,                  AsW + s * 4096);
        async16(Ap + (size_t)64 * K, AsW + s * 4096 + 64 * 32);
        async16(Bp,                  BsW + s * 2048);
        Ap += 32; Bp += 32;
    }
    WAITV("6"); SCHED0(); SBAR();
    int cur = 0;
    for (int t0 = 0; t0 + 3 < NT_; ++t0) {
        short8 a[4], b[2];
        const u16* aB = As + cur * 4096 + aoff;
        const u16* bB = Bs + cur * 2048 + boff;
#pragma unroll
        for (int i = 0; i < 4; i++) a[i] = *(const short8*)(aB + i * 16 * 32);
#pragma unroll
        for (int j = 0; j < 2; j++) b[j] = *(const short8*)(bB + j * 16 * 32);
        WAITL(); SCHED0(); SBAR();
        async16(Ap,                  AsW + cur * 4096);
        async16(Ap + (size_t)64 * K, AsW + cur * 4096 + 64 * 32);
        async16(Bp,                  BsW + cur * 2048);
        Ap += 32; Bp += 32;
#pragma unroll
        for (int i = 0; i < 4; i++)
#pragma unroll
            for (int j = 0; j < 2; j++)
                acc[i][j] = __builtin_amdgcn_mfma_f32_16x16x32_bf16(
                    a[i], b[j], acc[i][j], 0, 0, 0);
        WAITV("6"); SCHED0(); SBAR();
        cur = cur + 1; if (cur == 3) cur = 0;
    }
#pragma unroll
    for (int tail = 0; tail < 3; tail++) {
        short8 a[4], b[2];
        const u16* aB = As + cur * 4096 + aoff;
        const u16* bB = Bs + cur * 2048 + boff;
#pragma unroll
        for (int i = 0; i < 4; i++) a[i] = *(const short8*)(aB + i * 16 * 32);
#pragma unroll
        for (int j = 0; j < 2; j++) b[j] = *(const short8*)(bB + j * 16 * 32);
#pragma unroll
        for (int i = 0; i < 4; i++)
#pragma unroll
            for (int j = 0; j < 2; j++)
                acc[i][j] = __builtin_amdgcn_mfma_f32_16x16x32_bf16(
                    a[i], b[j], acc[i][j], 0, 0, 0);
        if (tail == 0) { WAITV("3"); SCHED0(); SBAR(); }
        if (tail == 1) { WAITV("0"); SCHED0(); SBAR(); }
        cur = cur + 1; if (cur == 3) cur = 0;
    }
#pragma unroll
    for (int j = 0; j < 2; j++) {
        const int n = n0 + wn + j * 16 + col;
        const float bn = bias[n];
#pragma unroll
        for (int i = 0; i < 4; i++) {
#pragma unroll
            for (int r = 0; r < 4; r++) {
                const int m = m0 + wm + i * 16 + qk * 4 + r;
                float v = acc[i][j][r] + bn;
                if (RES == 1) v += ((const float*)res)[(size_t)m * N + n];
                if (RES == 2) v += bu2f(((const u16*)res)[(size_t)m * N + n]);
                if (OMODE == 0) ((float*)Cout)[(size_t)m * N + n] = v;
                if (OMODE == 1) ((u16*)Cout)[(size_t)m * N + n] = f2bu(v);
            }
        }
    }
}

// =================== f16 MFMA fused sparse attention (v6, R4-best) ===========
// Reverted to the R4 measured-best (82.8us): fused QK^T->LDS (no sc[32]),
// xq[9], 4-way PV accumulators, setprio. R5's reg-prefetch was a slight
// regression (compiler already schedules loads early) - removed.
__global__ __launch_bounds__(256, 5)
void attn_small(const u16* __restrict__ qb, const u16* __restrict__ kb,
                const u16* __restrict__ vT, const int* __restrict__ nkbuf,
                u16* __restrict__ att)
{
    const int nk = nkbuf[0];
    if (nk > 1152) return;              // big-path kernel handles this
    __shared__ u16 Plds[16 * 1024];     // 32 KB: scores, then P
    const int NS = (nk + 127) >> 7;     // active 128-key register slots (1..9)
    const int NT = (nk + 31) >> 5;      // active 32-key PV tiles (1..36)
    const int hh = blockIdx.x >> 7;
    const int q0 = (blockIdx.x & 127) * 16;
    const int t  = threadIdx.x;
    const int w  = __builtin_amdgcn_readfirstlane(t >> 6);   // wave id -> SGPR
    const int l  = t & 63;
    const int lg = l >> 4, lc = l & 15;
    const _Float16 NEG = (_Float16)(-30000.f);
    const half4v NEG4 = {NEG, NEG, NEG, NEG};

    // Q as B-operand: B[n=lc (q-row)][k=lg*8+j]
    const u16* qp = qb + (size_t)(q0 + lc) * D + hh * HD + lg * 8;
    const half8v bq0 = *(const half8v*)qp;
    const half8v bq1 = *(const half8v*)(qp + 32);
    const u16* kbase = kb + hh * HD + lg * 8;

    // ---- Phase A: FUSED QK^T + transpose-write, tiles g=4T+w, keys [0,1024) --
#pragma unroll
    for (int T = 0; T < 16; T++) {
        const int g = 4 * T + w;
        if (g < 8 * NS) {               // tile's slot is active (wave-uniform)
            half4v scv;
            if ((g + 1) * 16 <= nk) {   // full tile: no per-key select
                const u16* kp = kbase + (size_t)(g * 16 + lc) * D;
                floatx4 a = (floatx4)0.f;
                a = mfma_f16(*(const half8v*)kp,        bq0, a);   // A = K !
                a = mfma_f16(*(const half8v*)(kp + 32), bq1, a);
                half2v p01 = pkrtz(a[0] * 0.0625f, a[1] * 0.0625f);
                half2v p23 = pkrtz(a[2] * 0.0625f, a[3] * 0.0625f);
                scv = __builtin_shufflevector(p01, p23, 0, 1, 2, 3);
            } else if (g * 16 < nk) {   // boundary tile: mask keys >= nk
                const u16* kp = kbase + (size_t)(g * 16 + lc) * D;
                floatx4 a = (floatx4)0.f;
                a = mfma_f16(*(const half8v*)kp,        bq0, a);
                a = mfma_f16(*(const half8v*)(kp + 32), bq1, a);
                const int kb0 = g * 16 + lg * 4;
                half2v p01 = pkrtz(kb0 + 0 < nk ? a[0] * 0.0625f : -30000.f,
                                   kb0 + 1 < nk ? a[1] * 0.0625f : -30000.f);
                half2v p23 = pkrtz(kb0 + 2 < nk ? a[2] * 0.0625f : -30000.f,
                                   kb0 + 3 < nk ? a[3] * 0.0625f : -30000.f);
                scv = __builtin_shufflevector(p01, p23, 0, 1, 2, 3);
            } else {
                scv = NEG4;             // garbage slot-tail -> -30000
            }
            const int kl = g * 16 + lg * 4;
            const int b  = kl >> 3;
            const int p  = b ^ ((b >> 3) & 7) ^ (lc & 7);
            *(half4v*)&Plds[lc * 1024 + p * 8 + (lg & 1) * 4] = scv;
        }
    }
    __syncthreads();

    // ---- transpose-read: lane owns row R; slot s = keys [128s,128s+128) ----
    const int R = 4 * w + lg;
    half8v xq[9];
#pragma unroll
    for (int s = 0; s < 8; s++) {
        if (s < NS) {
            const int b = 16 * s + lc;
            const int p = b ^ ((b >> 3) & 7) ^ (R & 7);
            xq[s] = *(const half8v*)&Plds[R * 1024 + p * 8];
        }
    }
    if (NS > 8) {                       // slot 8: keys [1024, 1152) via chunk
        __syncthreads();                // all reads of slot-0 region done
#pragma unroll
        for (int T = 16; T < 18; T++) {
            const int g = 4 * T + w;
            half4v scv;
            if ((g + 1) * 16 <= nk) {
                const u16* kp = kbase + (size_t)(g * 16 + lc) * D;
                floatx4 a = (floatx4)0.f;
                a = mfma_f16(*(const half8v*)kp,        bq0, a);
                a = mfma_f16(*(const half8v*)(kp + 32), bq1, a);
                half2v p01 = pkrtz(a[0] * 0.0625f, a[1] * 0.0625f);
                half2v p23 = pkrtz(a[2] * 0.0625f, a[3] * 0.0625f);
                scv = __builtin_shufflevector(p01, p23, 0, 1, 2, 3);
            } else if (g * 16 < nk) {
                const u16* kp = kbase + (size_t)(g * 16 + lc) * D;
                floatx4 a = (floatx4)0.f;
                a = mfma_f16(*(const half8v*)kp,        bq0, a);
                a = mfma_f16(*(const half8v*)(kp + 32), bq1, a);
                const int kb0 = g * 16 + lg * 4;
                half2v p01 = pkrtz(kb0 + 0 < nk ? a[0] * 0.0625f : -30000.f,
                                   kb0 + 1 < nk ? a[1] * 0.0625f : -30000.f);
                half2v p23 = pkrtz(kb0 + 2 < nk ? a[2] * 0.0625f : -30000.f,
                                   kb0 + 3 < nk ? a[3] * 0.0625f : -30000.f);
                scv = __builtin_shufflevector(p01, p23, 0, 1, 2, 3);
            } else {
                scv = NEG4;
            }
            const int kl = g * 16 + lg * 4 - 1024;   // chunk-local
            const int b  = kl >> 3;
            const int p  = b ^ ((b >> 3) & 7) ^ (lc & 7);
            *(half4v*)&Plds[lc * 1024 + p * 8 + (lg & 1) * 4] = scv;
        }
        __syncthreads();
        {
            const int b = lc;           // chunk-local slot read (s=0 form)
            const int p = b ^ ((b >> 3) & 7) ^ (R & 7);
            xq[8] = *(const half8v*)&Plds[R * 1024 + p * 8];
        }
    }

    // ---- row max over active slots (in-lane + DPP 16-lane reduce) ----
    float tau;
    {
        half8v m8 = xq[0];              // slot 0 always active (nk >= 1)
#pragma unroll
        for (int i = 1; i < 9; i++)
            if (i < NS) m8 = __builtin_elementwise_max(m8, xq[i]);
        union { half8v v; half2v h[4]; } u; u.v = m8;
        half2v m2 = __builtin_elementwise_max(
            __builtin_elementwise_max(u.h[0], u.h[1]),
            __builtin_elementwise_max(u.h[2], u.h[3]));
        float mx = fmaxf((float)m2[0], (float)m2[1]);
        mx = rowmax16(mx);
        tau = mx - 1.0f;                // g(tau0) >= 1 -> monotone Newton
    }

    // ---- Newton, early-exit, ZERO barriers: g(tau) = sum relu(x-tau)^2 = 1 --
    const half2v one2 = {(_Float16)1.f, (_Float16)1.f};
    const float nact = (float)(8 * NS);
#pragma unroll 1
    for (int it = 0; it < 12; it++) {
        const _Float16 th = (_Float16)tau;
        const float tf = (float)th;      // exact f32 image of the f16 tau
        const half8v t8 = {th, th, th, th, th, th, th, th};
        float m1a = 0.f, m1b = 0.f, m2a = 0.f, m2b = 0.f;
#pragma unroll
        for (int i = 0; i < 9; i++) {
            if (i < NS) {
                union { half8v v; half2v h[4]; } u;
                u.v = __builtin_elementwise_max(xq[i], t8);   // m = max(x, tau)
                m1a = fdot2f(u.h[0], one2, m1a);
                m2a = fdot2f(u.h[0], u.h[0], m2a);
                m1b = fdot2f(u.h[1], one2, m1b);
                m2b = fdot2f(u.h[1], u.h[1], m2b);
                m1a = fdot2f(u.h[2], one2, m1a);
                m2a = fdot2f(u.h[2], u.h[2], m2a);
                m1b = fdot2f(u.h[3], one2, m1b);
                m2b = fdot2f(u.h[3], u.h[3], m2b);
            }
        }
        const float M1 = m1a + m1b, M2 = m2a + m2b;
        float s1 = fmaf(-nact, tf, M1);
        float s2 = fmaf(tf, fmaf(nact, tf, -2.f * M1), M2);
        s1 = rowsum16(s1);
        s2 = rowsum16(s2);
        const float delta = (s2 - 1.0f) / (2.0f * fmaxf(s1, 1e-4f));
        tau += delta;
        if (__all(fabsf(delta) < 2.5e-4f)) break;
    }

    // ---- P = relu(x-tau)^2 in-place (same self-owned slots) + PV ----
    const _Float16 th = (_Float16)tau;
    const half8v t8 = {th, th, th, th, th, th, th, th};
    const half8v z8 = (half8v)(_Float16)0.f;
    floatx4 oa0 = (floatx4)0.f, oa1 = (floatx4)0.f;
    floatx4 oa2 = (floatx4)0.f, oa3 = (floatx4)0.f;
    const u16* vp = vT + (size_t)(hh * HD + w * 16 + lc) * S + lg * 8;
#pragma unroll
    for (int s = 0; s < 8; s++) {
        if (s < NS) {
            half8v dp = __builtin_elementwise_max(xq[s] - t8, z8);
            const int b = 16 * s + lc;
            const int p = b ^ ((b >> 3) & 7) ^ (R & 7);
            *(half8v*)&Plds[R * 1024 + p * 8] = dp * dp;
        }
    }
    __syncthreads();
    __builtin_amdgcn_s_setprio(1);
#pragma unroll
    for (int kt = 0; kt < 32; kt++) {
        if (kt < NT) {
            const int b = kt * 4 + lg;
            const int p = b ^ ((b >> 3) & 7) ^ (lc & 7);
            half8v af = *(const half8v*)&Plds[lc * 1024 + p * 8];  // A: P[row=lc]
            half8v bf = *(const half8v*)(vp + kt * 32);            // B: V^T[d]
            if ((kt & 3) == 0)      oa0 = mfma_f16(af, bf, oa0);
            else if ((kt & 3) == 1) oa1 = mfma_f16(af, bf, oa1);
            else if ((kt & 3) == 2) oa2 = mfma_f16(af, bf, oa2);
            else                    oa3 = mfma_f16(af, bf, oa3);
        }
    }
    __builtin_amdgcn_s_setprio(0);
    if (NS > 8) {                       // slot-8 P via chunk, PV tiles 32..35
        __syncthreads();                // PV reads of slot-0 region done
        {
            half8v dp = __builtin_elementwise_max(xq[8] - t8, z8);
            const int b = lc;
            const int p = b ^ ((b >> 3) & 7) ^ (R & 7);
            *(half8v*)&Plds[R * 1024 + p * 8] = dp * dp;
        }
        __syncthreads();
        const u16* vph = vp + 1024;
#pragma unroll
        for (int kt2 = 0; kt2 < 4; kt2++) {
            if (32 + kt2 < NT) {
                const int b = kt2 * 4 + lg;
                const int p = b ^ ((b >> 3) & 7) ^ (lc & 7);
                half8v af = *(const half8v*)&Plds[lc * 1024 + p * 8];
                half8v bf = *(const half8v*)(vph + kt2 * 32);
                if ((kt2 & 3) == 0)      oa0 = mfma_f16(af, bf, oa0);
                else if ((kt2 & 3) == 1) oa1 = mfma_f16(af, bf, oa1);
                else if ((kt2 & 3) == 2) oa2 = mfma_f16(af, bf, oa2);
                else                     oa3 = mfma_f16(af, bf, oa3);
            }
        }
    }
    const floatx4 oacc = (oa0 + oa1) + (oa2 + oa3);
#pragma unroll
    for (int r = 0; r < 4; r++)
        att[(size_t)(q0 + lg * 4 + r) * D + hh * HD + w * 16 + lc] = f2bu(oacc[r]);
}

// ---- big-nk fallback (nk > 1152; P ~ 2e-4 for this data) --------------------
__global__ __launch_bounds__(256, 5)
void attn_f16(const u16* __restrict__ qb, const u16* __restrict__ kb,
              const u16* __restrict__ vT, const int* __restrict__ nkbuf,
              u16* __restrict__ att)
{
    const int nk = nkbuf[0];
    if (nk <= 1152) return;             // small-path kernel handled it
    __shared__ u16 Plds[16 * 1024];
    const int NS = (nk + 127) >> 7;
    const int NT = (nk + 31) >> 5;
    const int hh = blockIdx.x >> 7;
    const int q0 = (blockIdx.x & 127) * 16;
    const int t  = threadIdx.x;
    const int w  = __builtin_amdgcn_readfirstlane(t >> 6);
    const int l  = t & 63;
    const int lg = l >> 4, lc = l & 15;
    const _Float16 NEG = (_Float16)(-30000.f);

    const u16* qp = qb + (size_t)(q0 + lc) * D + hh * HD + lg * 8;
    const half8v bq0 = *(const half8v*)qp;
    const half8v bq1 = *(const half8v*)(qp + 32);

    half4v sc[32];
    {
        const u16* kbase = kb + hh * HD + lg * 8;
        __builtin_amdgcn_s_setprio(1);
#pragma unroll
        for (int T = 0; T < 32; T++) {
            const int g = 4 * T + w;
            if (g * 16 < nk) {
                const u16* kp = kbase + (size_t)(g * 16 + lc) * D;
                floatx4 a = (floatx4)0.f;
                a = mfma_f16(*(const half8v*)kp,        bq0, a);
                a = mfma_f16(*(const half8v*)(kp + 32), bq1, a);
                const int kb0 = g * 16 + lg * 4;
                half2v p01 = pkrtz(kb0 + 0 < nk ? a[0] * 0.0625f : -30000.f,
                                   kb0 + 1 < nk ? a[1] * 0.0625f : -30000.f);
                half2v p23 = pkrtz(kb0 + 2 < nk ? a[2] * 0.0625f : -30000.f,
                                   kb0 + 3 < nk ? a[3] * 0.0625f : -30000.f);
                sc[T] = __builtin_shufflevector(p01, p23, 0, 1, 2, 3);
            } else {
                sc[T] = (half4v){NEG, NEG, NEG, NEG};
            }
        }
        __builtin_amdgcn_s_setprio(0);
    }

    const int R = 4 * w + lg;
    half8v xq[16];
    {
#pragma unroll
        for (int T = 0; T < 16; T++) {
            const int g  = 4 * T + w;
            const int kl = g * 16 + lg * 4;
            const int b  = kl >> 3;
            const int p  = b ^ ((b >> 3) & 7) ^ (lc & 7);
            *(half4v*)&Plds[lc * 1024 + p * 8 + (lg & 1) * 4] = sc[T];
        }
        __syncthreads();
#pragma unroll
        for (int s = 0; s < 8; s++) {
            if (s < NS) {
                const int b = 16 * s + lc;
                const int p = b ^ ((b >> 3) & 7) ^ (R & 7);
                xq[s] = *(const half8v*)&Plds[R * 1024 + p * 8];
            }
        }
        __syncthreads();
#pragma unroll
        for (int T = 16; T < 32; T++) {
            const int g  = 4 * T + w;
            const int kl = g * 16 + lg * 4 - 1024;
            const int b  = kl >> 3;
            const int p  = b ^ ((b >> 3) & 7) ^ (lc & 7);
            *(half4v*)&Plds[lc * 1024 + p * 8 + (lg & 1) * 4] = sc[T];
        }
        __syncthreads();
#pragma unroll
        for (int s = 0; s < 8; s++) {
            const int j = 8 + s;
            if (j < NS) {
                const int b = 16 * s + lc;
                const int p = b ^ ((b >> 3) & 7) ^ (R & 7);
                xq[j] = *(const half8v*)&Plds[R * 1024 + p * 8];
            }
        }
    }

    float tau;
    {
        half8v m8 = xq[0];
#pragma unroll
        for (int i = 1; i < 16; i++)
            if (i < NS) m8 = __builtin_elementwise_max(m8, xq[i]);
        union { half8v v; half2v h[4]; } u; u.v = m8;
        half2v m2 = __builtin_elementwise_max(
            __builtin_elementwise_max(u.h[0], u.h[1]),
            __builtin_elementwise_max(u.h[2], u.h[3]));
        float mx = fmaxf((float)m2[0], (float)m2[1]);
        mx = rowmax16(mx);
        tau = mx - 1.0f;
    }

    const half2v one2 = {(_Float16)1.f, (_Float16)1.f};
    const float nact = (float)(8 * NS);
#pragma unroll 1
    for (int it = 0; it < 12; it++) {
        const _Float16 th = (_Float16)tau;
        const float tf = (float)th;
        const half8v t8 = {th, th, th, th, th, th, th, th};
        float m1a = 0.f, m1b = 0.f, m2a = 0.f, m2b = 0.f;
#pragma unroll
        for (int i = 0; i < 16; i++) {
            if (i < NS) {
                union { half8v v; half2v h[4]; } u;
                u.v = __builtin_elementwise_max(xq[i], t8);
                m1a = fdot2f(u.h[0], one2, m1a);
                m2a = fdot2f(u.h[0], u.h[0], m2a);
                m1b = fdot2f(u.h[1], one2, m1b);
                m2b = fdot2f(u.h[1], u.h[1], m2b);
                m1a = fdot2f(u.h[2], one2, m1a);
                m2a = fdot2f(u.h[2], u.h[2], m2a);
                m1b = fdot2f(u.h[3], one2, m1b);
                m2b = fdot2f(u.h[3], u.h[3], m2b);
            }
        }
        const float M1 = m1a + m1b, M2 = m2a + m2b;
        float s1 = fmaf(-nact, tf, M1);
        float s2 = fmaf(tf, fmaf(nact, tf, -2.f * M1), M2);
        s1 = rowsum16(s1);
        s2 = rowsum16(s2);
        const float delta = (s2 - 1.0f) / (2.0f * fmaxf(s1, 1e-4f));
        tau += delta;
        if (__all(fabsf(delta) < 2.5e-4f)) break;
    }

    const _Float16 th = (_Float16)tau;
    const half8v t8 = {th, th, th, th, th, th, th, th};
    const half8v z8 = (half8v)(_Float16)0.f;
    floatx4 oa0 = (floatx4)0.f, oa1 = (floatx4)0.f;
    floatx4 oa2 = (floatx4)0.f, oa3 = (floatx4)0.f;
    const u16* vp = vT + (size_t)(hh * HD + w * 16 + lc) * S + lg * 8;
#pragma unroll
    for (int s = 0; s < 8; s++) {
        if (s < NS) {
            half8v dp = __builtin_elementwise_max(xq[s] - t8, z8);
            const int b = 16 * s + lc;
            const int p = b ^ ((b >> 3) & 7) ^ (R & 7);
            *(half8v*)&Plds[R * 1024 + p * 8] = dp * dp;
        }
    }
    __syncthreads();
    __builtin_amdgcn_s_setprio(1);
#pragma unroll
    for (int kt = 0; kt < 32; kt++) {
        if (kt < NT) {
            const int b = kt * 4 + lg;
            const int p = b ^ ((b >> 3) & 7) ^ (lc & 7);
            half8v af = *(const half8v*)&Plds[lc * 1024 + p * 8];
            half8v bf = *(const half8v*)(vp + kt * 32);
            if ((kt & 3) == 0)      oa0 = mfma_f16(af, bf, oa0);
            else if ((kt & 3) == 1) oa1 = mfma_f16(af, bf, oa1);
            else if ((kt & 3) == 2) oa2 = mfma_f16(af, bf, oa2);
            else                    oa3 = mfma_f16(af, bf, oa3);
        }
    }
    __builtin_amdgcn_s_setprio(0);
    {
        __syncthreads();
#pragma unroll
        for (int s = 0; s < 8; s++) {
            const int j = 8 + s;
            if (j < NS) {
                half8v dp = __builtin_elementwise_max(xq[j] - t8, z8);
                const int b = 16 * s + lc;
                const int p = b ^ ((b >> 3) & 7) ^ (R & 7);
                *(half8v*)&Plds[R * 1024 + p * 8] = dp * dp;
            }
        }
        __syncthreads();
        const u16* vph = vp + 1024;
        __builtin_amdgcn_s_setprio(1);
#pragma unroll
        for (int kt = 0; kt < 32; kt++) {
            if (32 + kt < NT) {
                const int b = kt * 4 + lg;
                const int p = b ^ ((b >> 3) & 7) ^ (lc & 7);
                half8v af = *(const half8v*)&Plds[lc * 1024 + p * 8];
                half8v bf = *(const half8v*)(vph + kt * 32);
                if ((kt & 3) == 0)      oa0 = mfma_f16(af, bf, oa0);
                else if ((kt & 3) == 1) oa1 = mfma_f16(af, bf, oa1);
                else if ((kt & 3) == 2) oa2 = mfma_f16(af, bf, oa2);
                else                    oa3 = mfma_f16(af, bf, oa3);
            }
        }
        __builtin_amdgcn_s_setprio(0);
    }
    const floatx4 oacc = (oa0 + oa1) + (oa2 + oa3);
#pragma unroll
    for (int r = 0; r < 4; r++)
        att[(size_t)(q0 + lg * 4 + r) * D + hh * HD + w * 16 + lc] = f2bu(oacc[r]);
}

// ---------------- host side ---------------------------------------------------
extern "C" void kernel_launch(void* const* d_in, const int* in_sizes, int n_in,
                              void* d_out, int out_size, void* d_ws, size_t ws_size,
                              hipStream_t stream)
{
    const float* inp  = (const float*)d_in[0];
    const int*   mask = (const int*)d_in[1];
    const float* wq   = (const float*)d_in[2];
    const float* bq   = (const float*)d_in[3];
    const float* wk   = (const float*)d_in[4];
    const float* bk   = (const float*)d_in[5];
    const float* wv   = (const float*)d_in[6];
    const float* bv   = (const float*)d_in[7];
    const float* wo   = (const float*)d_in[8];
    const float* bo   = (const float*)d_in[9];
    const float* ln1a = (const float*)d_in[10];
    const float* ln1b = (const float*)d_in[11];
    const float* w1   = (const float*)d_in[12];
    const float* b1   = (const float*)d_in[13];
    const float* w2   = (const float*)d_in[14];
    const float* b2   = (const float*)d_in[15];
    const float* ln2a = (const float*)d_in[16];
    const float* ln2b = (const float*)d_in[17];

    const size_t MB = 1u << 20;
    char* w = (char*)d_ws;
    // 32 MB overlay (16-bit bufs unless noted):
    //  [0,8):  wqkvb(6MB) -> w1b (after QKV) -> w2b (after FFN1)
    //  [8,12): x1 -> att -> x2   (bf16)
    //  [12,16): qb_ (f16) -> yb (bf16)
    //  [16,20): kb_ (f16)  \
    //  [20,24): vTb (f16)   > dead after attn -> hb [16,32)
    //  [24,26): wob (bf16) /  (dead after WO, before FFN1 writes hb)
    //  [26, 26MB+8KB+4): newpos int[2048] + nk  (dead before FFN1 writes hb)
    u16* wqkvb = (u16*)(w + 0 * MB);
    u16* w1b   = (u16*)(w + 0 * MB);
    u16* w2b   = (u16*)(w + 0 * MB);
    u16* x1    = (u16*)(w + 8 * MB);
    u16* att   = x1;
    u16* x2    = x1;
    u16* qb_   = (u16*)(w + 12 * MB);
    u16* yb    = (u16*)(w + 12 * MB);
    u16* kb_   = (u16*)(w + 16 * MB);
    u16* vTb   = (u16*)(w + 20 * MB);
    u16* wob   = (u16*)(w + 24 * MB);
    u16* hb    = (u16*)(w + 16 * MB);
    int* np    = (int*)(w + 26 * MB);
    int* nkbuf = np + 2048;
    float* outF = (float*)d_out;

    // -1. key-compaction scan (mask only)
    scan_mask_kernel<<<1, 256, 0, stream>>>(mask, np, nkbuf);
    // 0. weight conversions: QKV concat + WO
    cvt_kernel<<<1024, 256, 0, stream>>>(wq, wqkvb,                   (D * D) / 4);
    cvt_kernel<<<1024, 256, 0, stream>>>(wk, wqkvb + 1024 * 1024,     (D * D) / 4);
    cvt_kernel<<<1024, 256, 0, stream>>>(wv, wqkvb + 2 * 1024 * 1024, (D * D) / 4);
    cvt_kernel<<<1024, 256, 0, stream>>>(wo, wob, (D * D) / 4);
    // 1. LN1 -> bf16
    ln_kernel<float><<<S, 256, 0, stream>>>(inp, ln1a, ln1b, x1);
    // 2. fused QKV projection -> f16 Q [S,D]; K [S,D], V^T [D,S] permuted
    gemm_qkv<<<dim3(3 * D / 128, S / 128), 256, 0, stream>>>(
        x1, wqkvb, bq, bk, bv, np, qb_, kb_, vTb);
    // 3. convert w1 (wqkvb dead)
    cvt_kernel<<<4096, 256, 0, stream>>>(w1, w1b, (DFF * D) / 4);
    // 4. f16 MFMA fused entmax attention (compacted keys) -> att bf16
    attn_small<<<NH * (S / 16), 256, 0, stream>>>(qb_, kb_, vTb, nkbuf, att);
    attn_f16<<<NH * (S / 16), 256, 0, stream>>>(qb_, kb_, vTb, nkbuf, att);
    // 5. WO projection + residual(inp fp32) -> yb bf16  (256 blocks)
    gemm_mfma64<1, 1><<<dim3(D / 64, S / 128), 256, 0, stream>>>(
        att, wob, bo, inp, yb, S, D, D);
    // 6. LN2 -> x2 (att dead)
    ln_kernel<u16><<<S, 256, 0, stream>>>(yb, ln2a, ln2b, x2);
    // 7. FFN1 (+ReLU) -> hb bf16 (kb_/vTb/wob/np dead)
    gemm_mfma<1, true, 0><<<dim3(DFF / 128, S / 128), 256, 0, stream>>>(
        x2, w1b, b1, nullptr, hb, S, DFF, D);
    // 8. convert w2 (w1b dead)
    cvt_kernel<<<4096, 256, 0, stream>>>(w2, w2b, (DFF * D) / 4);
    // 9. FFN2 + residual(yb bf16) -> fp32 out  (256 blocks)
    gemm_mfma64<0, 2><<<dim3(D / 64, S / 128), 256, 0, stream>>>(
        hb, w2b, b2, yb, outF, S, D, DFF);
}

// Round 7
// 324.120 us; speedup vs baseline: 1.1101x; 1.0504x over previous
//
#include <hip/hip_runtime.h>
#include <hip/hip_bf16.h>

// Problem dims (fixed by setup_inputs)
#define S   2048
#define D   1024
#define DFF 4096
#define NH  16
#define HD  64

typedef unsigned short u16;
typedef unsigned int   u32;
typedef __attribute__((ext_vector_type(8))) short      short8;  // 8 bf16
typedef __attribute__((ext_vector_type(4))) float      floatx4; // MFMA C/D
typedef __attribute__((ext_vector_type(2))) _Float16   half2v;
typedef __attribute__((ext_vector_type(4))) _Float16   half4v;
typedef __attribute__((ext_vector_type(8))) _Float16   half8v;

__device__ __forceinline__ float bu2f(u16 u) {
    union { u32 i; float f; } x; x.i = ((u32)u) << 16; return x.f;
}
__device__ __forceinline__ u16 f2bu(float f) {
    __hip_bfloat16 h = __float2bfloat16(f);
    return *(u16*)&h;
}
__device__ __forceinline__ u16 f2h(float f) {
    _Float16 h = (_Float16)f; return *(u16*)&h;
}
__device__ __forceinline__ float ldf(const float* p) { return *p; }
__device__ __forceinline__ float ldf(const u16* p)   { return bu2f(*p); }

// cvt_pkrtz returns __fp16x2; bit-cast to our _Float16x2 (same 32-bit reg)
__device__ __forceinline__ half2v pkrtz(float a, float b) {
    auto v = __builtin_amdgcn_cvt_pkrtz(a, b);
    union { decltype(v) i; half2v o; } u; u.i = v; return u.o;
}

__device__ __forceinline__ floatx4 mfma_f16(half8v a, half8v b, floatx4 c) {
    return __builtin_amdgcn_mfma_f32_16x16x32_f16(a, b, c, 0, 0, 0);
}
__device__ __forceinline__ float fdot2f(half2v a, half2v b, float c) {
#if __has_builtin(__builtin_amdgcn_fdot2)
    return __builtin_amdgcn_fdot2(a, b, c, false);
#else
    return c + (float)a[0] * (float)b[0] + (float)a[1] * (float)b[1];
#endif
}

// ---- DPP 16-lane row reductions (VALU-speed, replaces ds_swizzle chains) ----
template <int K>
__device__ __forceinline__ float ror16f(float v) {
    int s = __builtin_bit_cast(int, v);
    int r = __builtin_amdgcn_update_dpp(s, s, 0x120 | K, 0xF, 0xF, false);
    return __builtin_bit_cast(float, r);
}
__device__ __forceinline__ float rowsum16(float v) {
    v += ror16f<1>(v);
    v += ror16f<2>(v);
    v += ror16f<4>(v);
    v += ror16f<8>(v);
    return v;
}
__device__ __forceinline__ float rowmax16(float v) {
    v = fmaxf(v, ror16f<1>(v));
    v = fmaxf(v, ror16f<2>(v));
    v = fmaxf(v, ror16f<4>(v));
    v = fmaxf(v, ror16f<8>(v));
    return v;
}

// async global->LDS, 16B per lane, lands at ldsbase + lane*16
__device__ __forceinline__ void async16(const void* g, void* l) {
    __builtin_amdgcn_global_load_lds(
        (const __attribute__((address_space(1))) u32*)g,
        (__attribute__((address_space(3))) u32*)l, 16, 0, 0);
}

// pipeline primitives (counted vmcnt, raw barrier; rule #18: sched_barrier
// after every inline-asm wait)
#define WAITV(N) asm volatile("s_waitcnt vmcnt(" N ")" ::: "memory")
#define WAITL()  asm volatile("s_waitcnt lgkmcnt(0)" ::: "memory")
#define SBAR()   __builtin_amdgcn_s_barrier()
#define SCHED0() __builtin_amdgcn_sched_barrier(0)

// ---------------- fp32 -> bf16 bulk convert (weights) ------------------------
__global__ __launch_bounds__(256)
void cvt_kernel(const float* __restrict__ in, u16* __restrict__ out, int n4)
{
    int i = blockIdx.x * 256 + threadIdx.x;
    if (i < n4) {
        float4 v = ((const float4*)in)[i];
        ushort4 s;
        s.x = f2bu(v.x); s.y = f2bu(v.y); s.z = f2bu(v.z); s.w = f2bu(v.w);
        ((ushort4*)out)[i] = s;
    }
}

// ---------------- prep: scan (block 0) + cvt wq/wk/wv/wo (blocks 1..4096) ----
// R7: merges 5 dispatches into 1 (launch-gap cut). Scan: unmasked keys ->
// [0,nk) order-preserving, masked -> [nk,2048); attention is permutation-
// invariant over keys and masked keys' P == 0.
__global__ __launch_bounds__(256)
void prep_kernel(const int* __restrict__ mask, int* __restrict__ newpos,
                 int* __restrict__ nkbuf,
                 const float* __restrict__ wq, const float* __restrict__ wk,
                 const float* __restrict__ wv, const float* __restrict__ wo,
                 u16* __restrict__ wqkvb, u16* __restrict__ wob)
{
    const int blk = blockIdx.x;
    const int t = threadIdx.x;
    if (blk == 0) {
        __shared__ int ps[256];
        int loc[8];
        int s = 0;
#pragma unroll
        for (int j = 0; j < 8; j++) {
            loc[j] = s;
            s += (mask[t * 8 + j] != 0);
        }
        ps[t] = s;
        __syncthreads();
        for (int off = 1; off < 256; off <<= 1) {
            int v = (t >= off) ? ps[t - off] : 0;
            __syncthreads();
            ps[t] += v;
            __syncthreads();
        }
        const int total = ps[255];                 // nk
        const int base = t ? ps[t - 1] : 0;
#pragma unroll
        for (int j = 0; j < 8; j++) {
            const int gi = t * 8 + j;
            const int up = base + loc[j];          // unmasked rank
            newpos[gi] = mask[gi] ? up : (total + gi - up);
        }
        if (t == 0) nkbuf[0] = total;
    } else {
        int cb = blk - 1;                          // 0..4095, 1024 per weight
        const float* src;
        u16* dst;
        if (cb < 1024)      { src = wq; dst = wqkvb; }
        else if (cb < 2048) { src = wk; dst = wqkvb + 1024 * 1024; cb -= 1024; }
        else if (cb < 3072) { src = wv; dst = wqkvb + 2 * 1024 * 1024; cb -= 2048; }
        else                { src = wo; dst = wob; cb -= 3072; }
        const int i = cb * 256 + t;                // < (D*D)/4 = 262144
        float4 v = ((const float4*)src)[i];
        ushort4 sv;
        sv.x = f2bu(v.x); sv.y = f2bu(v.y); sv.z = f2bu(v.z); sv.w = f2bu(v.w);
        ((ushort4*)dst)[i] = sv;
    }
}

// ---------------- LayerNorm: one block per row, D=1024, 256 threads ----------
template <typename T>
__global__ __launch_bounds__(256, 4)
void ln_kernel(const T* __restrict__ in, const float* __restrict__ ga,
               const float* __restrict__ gb, u16* __restrict__ out)
{
    const int row = blockIdx.x;
    const int t = threadIdx.x;
    const T* x = in + (size_t)row * D;
    float v[4];
    float s = 0.f, ss = 0.f;
#pragma unroll
    for (int j = 0; j < 4; j++) {
        float val = ldf(x + t + 256 * j);
        v[j] = val; s += val; ss = fmaf(val, val, ss);
    }
#pragma unroll
    for (int off = 32; off >= 1; off >>= 1) {
        s  += __shfl_down(s,  off, 64);
        ss += __shfl_down(ss, off, 64);
    }
    __shared__ float red[10];
    const int wave = t >> 6, lane = t & 63;
    if (lane == 0) { red[wave] = s; red[4 + wave] = ss; }
    __syncthreads();
    if (t == 0) {
        float S1 = red[0] + red[1] + red[2] + red[3];
        float S2 = red[4] + red[5] + red[6] + red[7];
        float mu = S1 / (float)D;
        float var = (S2 - (float)D * mu * mu) / (float)(D - 1);  // ddof=1
        float sig = sqrtf(fmaxf(var, 0.f)) + 1e-6f;              // eps on sigma
        red[8] = mu; red[9] = 1.f / sig;
    }
    __syncthreads();
    const float mu = red[8], rs = red[9];
#pragma unroll
    for (int j = 0; j < 4; j++) {
        int c = t + 256 * j;
        out[(size_t)row * D + c] = f2bu((v[j] - mu) * rs * ga[c] + gb[c]);
    }
}

// ======================= MFMA GEMM core (128x128 tile) =======================
// 3-buffer, depth-2 global_load_lds pipeline (T3+T4 minimum form).
// Invariant entering iter t: stage t resident+certified; t+1, t+2 in flight.
// Never vmcnt(0) in the main loop; tail peels immediates 4 -> 0.
#define GEMM_CORE(A_, B_, K_)                                                   \
    __shared__ u16 As[3 * 128 * 32];                                            \
    __shared__ u16 Bs[3 * 128 * 32];                                            \
    const int t = threadIdx.x;                                                  \
    const int w = t >> 6, l = t & 63;                                           \
    const int m0 = blockIdx.y * 128, n0 = blockIdx.x * 128;                     \
    const int qk = l >> 4, col = l & 15;                                        \
    const int wm = (w & 1) * 64, wn = (w >> 1) * 64;                            \
    const int sr  = l >> 2;                                                     \
    const int sq  = l & 3;                                                      \
    const int row = w * 16 + sr;                                                \
    const int gq  = sq ^ ((row >> 1) & 3);                                      \
    const u16* Ap = A_ + (size_t)(m0 + row) * K_ + gq * 8;                      \
    const u16* Bp = B_ + (size_t)(n0 + row) * K_ + gq * 8;                      \
    u16* AsW = As + w * 16 * 32;                                                \
    u16* BsW = Bs + w * 16 * 32;                                                \
    const int mloc = wm + col, nloc = wn + col;                                 \
    const int aoff = mloc * 32 + (qk ^ ((mloc >> 1) & 3)) * 8;                  \
    const int boff = nloc * 32 + (qk ^ ((nloc >> 1) & 3)) * 8;                  \
    floatx4 acc[4][4];                                                          \
    _Pragma("unroll")                                                           \
    for (int i = 0; i < 4; i++)                                                 \
        _Pragma("unroll")                                                       \
        for (int j = 0; j < 4; j++) acc[i][j] = (floatx4)0.f;                   \
    const int NT_ = K_ / 32;                                                    \
    _Pragma("unroll")                                                           \
    for (int s = 0; s < 3; s++) {                                               \
        async16(Ap,                   AsW + s * 4096);                          \
        async16(Ap + (size_t)64 * K_, AsW + s * 4096 + 64 * 32);                \
        async16(Bp,                   BsW + s * 4096);                          \
        async16(Bp + (size_t)64 * K_, BsW + s * 4096 + 64 * 32);                \
        Ap += 32; Bp += 32;                                                     \
    }                                                                           \
    WAITV("8"); SCHED0(); SBAR();                                               \
    int cur = 0;                                                                \
    for (int t0 = 0; t0 + 3 < NT_; ++t0) {                                      \
        short8 a[4], b[4];                                                      \
        const u16* aB = As + cur * 4096 + aoff;                                 \
        const u16* bB = Bs + cur * 4096 + boff;                                 \
        _Pragma("unroll")                                                       \
        for (int i = 0; i < 4; i++) a[i] = *(const short8*)(aB + i * 16 * 32);  \
        _Pragma("unroll")                                                       \
        for (int j = 0; j < 4; j++) b[j] = *(const short8*)(bB + j * 16 * 32);  \
        WAITL(); SCHED0(); SBAR();                                              \
        async16(Ap,                   AsW + cur * 4096);                        \
        async16(Ap + (size_t)64 * K_, AsW + cur * 4096 + 64 * 32);              \
        async16(Bp,                   BsW + cur * 4096);                        \
        async16(Bp + (size_t)64 * K_, BsW + cur * 4096 + 64 * 32);              \
        Ap += 32; Bp += 32;                                                     \
        _Pragma("unroll")                                                       \
        for (int i = 0; i < 4; i++)                                             \
            _Pragma("unroll")                                                   \
            for (int j = 0; j < 4; j++)                                         \
                acc[i][j] = __builtin_amdgcn_mfma_f32_16x16x32_bf16(            \
                    a[i], b[j], acc[i][j], 0, 0, 0);                            \
        WAITV("8"); SCHED0(); SBAR();                                           \
        cur = cur + 1; if (cur == 3) cur = 0;                                   \
    }                                                                           \
    _Pragma("unroll")                                                           \
    for (int tail = 0; tail < 3; tail++) {                                      \
        short8 a[4], b[4];                                                      \
        const u16* aB = As + cur * 4096 + aoff;                                 \
        const u16* bB = Bs + cur * 4096 + boff;                                 \
        _Pragma("unroll")                                                       \
        for (int i = 0; i < 4; i++) a[i] = *(const short8*)(aB + i * 16 * 32);  \
        _Pragma("unroll")                                                       \
        for (int j = 0; j < 4; j++) b[j] = *(const short8*)(bB + j * 16 * 32);  \
        _Pragma("unroll")                                                       \
        for (int i = 0; i < 4; i++)                                             \
            _Pragma("unroll")                                                   \
            for (int j = 0; j < 4; j++)                                         \
                acc[i][j] = __builtin_amdgcn_mfma_f32_16x16x32_bf16(            \
                    a[i], b[j], acc[i][j], 0, 0, 0);                            \
        if (tail == 0) { WAITV("4"); SCHED0(); SBAR(); }                        \
        if (tail == 1) { WAITV("0"); SCHED0(); SBAR(); }                        \
        cur = cur + 1; if (cur == 3) cur = 0;                                   \
    }

// ---- generic GEMM 128x128 (+bias/relu/res), OMODE 0 f32 / 1 bf16 ------------
template <int OMODE, bool RELU, int RES>
__global__ __launch_bounds__(256, 2)
void gemm_mfma(const u16* __restrict__ A, const u16* __restrict__ B,
               const float* __restrict__ bias, const void* __restrict__ res,
               void* __restrict__ Cout, int M, int N, int K)
{
    GEMM_CORE(A, B, K)
#pragma unroll
    for (int j = 0; j < 4; j++) {
        const int n = n0 + wn + j * 16 + col;
        const float bn = bias[n];
#pragma unroll
        for (int i = 0; i < 4; i++) {
#pragma unroll
            for (int r = 0; r < 4; r++) {
                const int m = m0 + wm + i * 16 + qk * 4 + r;
                float v = acc[i][j][r] + bn;
                if (RELU) v = fmaxf(v, 0.f);
                if (RES == 1) v += ((const float*)res)[(size_t)m * N + n];
                if (RES == 2) v += bu2f(((const u16*)res)[(size_t)m * N + n]);
                if (OMODE == 0) ((float*)Cout)[(size_t)m * N + n] = v;
                if (OMODE == 1) ((u16*)Cout)[(size_t)m * N + n] = f2bu(v);
            }
        }
    }
}

// ---- fused QKV GEMM (128x128): f16 Q [S,D]; K,V^T written PERMUTED by np ----
__global__ __launch_bounds__(256, 2)
void gemm_qkv(const u16* __restrict__ A, const u16* __restrict__ B,
              const float* __restrict__ bq, const float* __restrict__ bk,
              const float* __restrict__ bv, const int* __restrict__ np,
              u16* __restrict__ outQ, u16* __restrict__ outK,
              u16* __restrict__ outVT)
{
    const int K = D;
    GEMM_CORE(A, B, K)
    const int seg   = n0 >> 10;
    const int nbase = n0 & 1023;
    const float* bs = (seg == 0) ? bq : (seg == 1) ? bk : bv;
    int npm[4][4];
    if (seg != 0) {
#pragma unroll
        for (int i = 0; i < 4; i++)
#pragma unroll
            for (int r = 0; r < 4; r++)
                npm[i][r] = np[m0 + wm + i * 16 + qk * 4 + r];
    }
#pragma unroll
    for (int j = 0; j < 4; j++) {
        const int nl = nbase + wn + j * 16 + col;
        const float bn = bs[nl];
#pragma unroll
        for (int i = 0; i < 4; i++) {
#pragma unroll
            for (int r = 0; r < 4; r++) {
                const int m = m0 + wm + i * 16 + qk * 4 + r;
                float v = acc[i][j][r] + bn;
                if (seg == 0)      outQ [(size_t)m * D + nl]          = f2h(v);
                else if (seg == 1) outK [(size_t)npm[i][r] * D + nl]  = f2h(v);
                else               outVT[(size_t)nl * S + npm[i][r]]  = f2h(v);
            }
        }
    }
}

// ---- 128x64-tile GEMM, same 3-buffer depth-2 pipeline (WO, FFN2) ------------
template <int OMODE, int RES>
__global__ __launch_bounds__(256, 2)
void gemm_mfma64(const u16* __restrict__ A, const u16* __restrict__ B,
                 const float* __restrict__ bias, const void* __restrict__ res,
                 void* __restrict__ Cout, int M, int N, int K)
{
    __shared__ u16 As[3 * 128 * 32];
    __shared__ u16 Bs[3 * 64 * 32];
    const int t = threadIdx.x;
    const int w = t >> 6, l = t & 63;
    const int m0 = blockIdx.y * 128, n0 = blockIdx.x * 64;
    const int qk = l >> 4, col = l & 15;
    const int wm = (w & 1) * 64, wn = (w >> 1) * 32;
    const int sr = l >> 2, sq = l & 3;
    const int row = w * 16 + sr;
    const int gq = sq ^ ((row >> 1) & 3);
    const u16* Ap = A + (size_t)(m0 + row) * K + gq * 8;
    const u16* Bp = B + (size_t)(n0 + row) * K + gq * 8;
    u16* AsW = As + w * 16 * 32;
    u16* BsW = Bs + w * 16 * 32;
    const int mloc = wm + col, nloc = wn + col;
    const int aoff = mloc * 32 + (qk ^ ((mloc >> 1) & 3)) * 8;
    const int boff = nloc * 32 + (qk ^ ((nloc >> 1) & 3)) * 8;
    floatx4 acc[4][2];
#pragma unroll
    for (int i = 0; i < 4; i++)
#pragma unroll
        for (int j = 0; j < 2; j++) acc[i][j] = (floatx4)0.f;
    const int NT_ = K / 32;
#pragma unroll
    for (int s = 0; s < 3; s++) {
        async16(Ap,                  AsW + s * 4096);
        async16(Ap + (size_t)64 * K, AsW + s * 4096 + 64 * 32);
        async16(Bp,                  BsW + s * 2048);
        Ap += 32; Bp += 32;
    }
    WAITV("6"); SCHED0(); SBAR();
    int cur = 0;
    for (int t0 = 0; t0 + 3 < NT_; ++t0) {
        short8 a[4], b[2];
        const u16* aB = As + cur * 4096 + aoff;
        const u16* bB = Bs + cur * 2048 + boff;
#pragma unroll
        for (int i = 0; i < 4; i++) a[i] = *(const short8*)(aB + i * 16 * 32);
#pragma unroll
        for (int j = 0; j < 2; j++) b[j] = *(const short8*)(bB + j * 16 * 32);
        WAITL(); SCHED0(); SBAR();
        async16(Ap,                  AsW + cur * 4096);
        async16(Ap + (size_t)64 * K, AsW + cur * 4096 + 64 * 32);
        async16(Bp,                  BsW + cur * 2048);
        Ap += 32; Bp += 32;
#pragma unroll
        for (int i = 0; i < 4; i++)
#pragma unroll
            for (int j = 0; j < 2; j++)
                acc[i][j] = __builtin_amdgcn_mfma_f32_16x16x32_bf16(
                    a[i], b[j], acc[i][j], 0, 0, 0);
        WAITV("6"); SCHED0(); SBAR();
        cur = cur + 1; if (cur == 3) cur = 0;
    }
#pragma unroll
    for (int tail = 0; tail < 3; tail++) {
        short8 a[4], b[2];
        const u16* aB = As + cur * 4096 + aoff;
        const u16* bB = Bs + cur * 2048 + boff;
#pragma unroll
        for (int i = 0; i < 4; i++) a[i] = *(const short8*)(aB + i * 16 * 32);
#pragma unroll
        for (int j = 0; j < 2; j++) b[j] = *(const short8*)(bB + j * 16 * 32);
#pragma unroll
        for (int i = 0; i < 4; i++)
#pragma unroll
            for (int j = 0; j < 2; j++)
                acc[i][j] = __builtin_amdgcn_mfma_f32_16x16x32_bf16(
                    a[i], b[j], acc[i][j], 0, 0, 0);
        if (tail == 0) { WAITV("3"); SCHED0(); SBAR(); }
        if (tail == 1) { WAITV("0"); SCHED0(); SBAR(); }
        cur = cur + 1; if (cur == 3) cur = 0;
    }
#pragma unroll
    for (int j = 0; j < 2; j++) {
        const int n = n0 + wn + j * 16 + col;
        const float bn = bias[n];
#pragma unroll
        for (int i = 0; i < 4; i++) {
#pragma unroll
            for (int r = 0; r < 4; r++) {
                const int m = m0 + wm + i * 16 + qk * 4 + r;
                float v = acc[i][j][r] + bn;
                if (RES == 1) v += ((const float*)res)[(size_t)m * N + n];
                if (RES == 2) v += bu2f(((const u16*)res)[(size_t)m * N + n]);
                if (OMODE == 0) ((float*)Cout)[(size_t)m * N + n] = v;
                if (OMODE == 1) ((u16*)Cout)[(size_t)m * N + n] = f2bu(v);
            }
        }
    }
}

// =================== unified attention + cvt-w1 tail (R7) ====================
// blocks [0,2048): attention, internal small/big switch on nk (block-uniform).
// blocks [2048,6144): cvt of w1 (f32->bf16) -- independent streaming work that
// backfills CUs while attn blocks stall (attn issue slots >50% idle; R4/R5
// showed latency/occupancy levers are dead, so hide OTHER work under it).
// launch_bounds(256,3): ~170-reg budget covers the big path without spill;
// attn is occupancy-insensitive (R3/R4), so the looser bound costs nothing.
// SPILL RULE: every loop touching reg arrays fully unrolled, static indices.
__global__ __launch_bounds__(256, 3)
void attn_cvt(const u16* __restrict__ qb, const u16* __restrict__ kb,
              const u16* __restrict__ vT, const int* __restrict__ nkbuf,
              u16* __restrict__ att,
              const float* __restrict__ w1src, u16* __restrict__ w1dst)
{
    __shared__ u16 Plds[16 * 1024];     // 32 KB: scores, then P (attn blocks)
    const int blk = blockIdx.x;
    const int t  = threadIdx.x;
    if (blk >= 2048) {                  // ---- cvt-w1 tail blocks ----
        const int i = (blk - 2048) * 256 + t;      // < (DFF*D)/4 = 1048576
        float4 v = ((const float4*)w1src)[i];
        ushort4 sv;
        sv.x = f2bu(v.x); sv.y = f2bu(v.y); sv.z = f2bu(v.z); sv.w = f2bu(v.w);
        ((ushort4*)w1dst)[i] = sv;
        return;
    }
    const int nk = nkbuf[0];            // uniform (scalar load)
    const int NS = (nk + 127) >> 7;     // active 128-key register slots
    const int NT = (nk + 31) >> 5;      // active 32-key PV tiles
    const int hh = blk >> 7;
    const int q0 = (blk & 127) * 16;
    const int w  = __builtin_amdgcn_readfirstlane(t >> 6);   // wave id -> SGPR
    const int l  = t & 63;
    const int lg = l >> 4, lc = l & 15;
    const _Float16 NEG = (_Float16)(-30000.f);
    const half4v NEG4 = {NEG, NEG, NEG, NEG};

    // Q as B-operand: B[n=lc (q-row)][k=lg*8+j]
    const u16* qp = qb + (size_t)(q0 + lc) * D + hh * HD + lg * 8;
    const half8v bq0 = *(const half8v*)qp;
    const half8v bq1 = *(const half8v*)(qp + 32);
    const u16* kbase = kb + hh * HD + lg * 8;
    const int R = 4 * w + lg;
    const half2v one2 = {(_Float16)1.f, (_Float16)1.f};
    const u16* vp = vT + (size_t)(hh * HD + w * 16 + lc) * S + lg * 8;

    if (nk <= 1152) {
        // =================== small path (nk <= 1152; P ~ 1-2e-4) =============
        // ---- Phase A: FUSED QK^T + transpose-write, keys [0,1024) ----
#pragma unroll
        for (int T = 0; T < 16; T++) {
            const int g = 4 * T + w;
            if (g < 8 * NS) {           // tile's slot is active (wave-uniform)
                half4v scv;
                if ((g + 1) * 16 <= nk) {
                    const u16* kp = kbase + (size_t)(g * 16 + lc) * D;
                    floatx4 a = (floatx4)0.f;
                    a = mfma_f16(*(const half8v*)kp,        bq0, a);   // A = K !
                    a = mfma_f16(*(const half8v*)(kp + 32), bq1, a);
                    half2v p01 = pkrtz(a[0] * 0.0625f, a[1] * 0.0625f);
                    half2v p23 = pkrtz(a[2] * 0.0625f, a[3] * 0.0625f);
                    scv = __builtin_shufflevector(p01, p23, 0, 1, 2, 3);
                } else if (g * 16 < nk) {
                    const u16* kp = kbase + (size_t)(g * 16 + lc) * D;
                    floatx4 a = (floatx4)0.f;
                    a = mfma_f16(*(const half8v*)kp,        bq0, a);
                    a = mfma_f16(*(const half8v*)(kp + 32), bq1, a);
                    const int kb0 = g * 16 + lg * 4;
                    half2v p01 = pkrtz(kb0 + 0 < nk ? a[0] * 0.0625f : -30000.f,
                                       kb0 + 1 < nk ? a[1] * 0.0625f : -30000.f);
                    half2v p23 = pkrtz(kb0 + 2 < nk ? a[2] * 0.0625f : -30000.f,
                                       kb0 + 3 < nk ? a[3] * 0.0625f : -30000.f);
                    scv = __builtin_shufflevector(p01, p23, 0, 1, 2, 3);
                } else {
                    scv = NEG4;
                }
                const int kl = g * 16 + lg * 4;
                const int b  = kl >> 3;
                const int p  = b ^ ((b >> 3) & 7) ^ (lc & 7);
                *(half4v*)&Plds[lc * 1024 + p * 8 + (lg & 1) * 4] = scv;
            }
        }
        __syncthreads();

        // ---- transpose-read: slot s = keys [128s,128s+128) ----
        half8v xq[9];
#pragma unroll
        for (int s = 0; s < 8; s++) {
            if (s < NS) {
                const int b = 16 * s + lc;
                const int p = b ^ ((b >> 3) & 7) ^ (R & 7);
                xq[s] = *(const half8v*)&Plds[R * 1024 + p * 8];
            }
        }
        if (NS > 8) {                   // slot 8: keys [1024,1152) via chunk
            __syncthreads();
#pragma unroll
            for (int T = 16; T < 18; T++) {
                const int g = 4 * T + w;
                half4v scv;
                if ((g + 1) * 16 <= nk) {
                    const u16* kp = kbase + (size_t)(g * 16 + lc) * D;
                    floatx4 a = (floatx4)0.f;
                    a = mfma_f16(*(const half8v*)kp,        bq0, a);
                    a = mfma_f16(*(const half8v*)(kp + 32), bq1, a);
                    half2v p01 = pkrtz(a[0] * 0.0625f, a[1] * 0.0625f);
                    half2v p23 = pkrtz(a[2] * 0.0625f, a[3] * 0.0625f);
                    scv = __builtin_shufflevector(p01, p23, 0, 1, 2, 3);
                } else if (g * 16 < nk) {
                    const u16* kp = kbase + (size_t)(g * 16 + lc) * D;
                    floatx4 a = (floatx4)0.f;
                    a = mfma_f16(*(const half8v*)kp,        bq0, a);
                    a = mfma_f16(*(const half8v*)(kp + 32), bq1, a);
                    const int kb0 = g * 16 + lg * 4;
                    half2v p01 = pkrtz(kb0 + 0 < nk ? a[0] * 0.0625f : -30000.f,
                                       kb0 + 1 < nk ? a[1] * 0.0625f : -30000.f);
                    half2v p23 = pkrtz(kb0 + 2 < nk ? a[2] * 0.0625f : -30000.f,
                                       kb0 + 3 < nk ? a[3] * 0.0625f : -30000.f);
                    scv = __builtin_shufflevector(p01, p23, 0, 1, 2, 3);
                } else {
                    scv = NEG4;
                }
                const int kl = g * 16 + lg * 4 - 1024;   // chunk-local
                const int b  = kl >> 3;
                const int p  = b ^ ((b >> 3) & 7) ^ (lc & 7);
                *(half4v*)&Plds[lc * 1024 + p * 8 + (lg & 1) * 4] = scv;
            }
            __syncthreads();
            {
                const int b = lc;
                const int p = b ^ ((b >> 3) & 7) ^ (R & 7);
                xq[8] = *(const half8v*)&Plds[R * 1024 + p * 8];
            }
        }

        // ---- row max ----
        float tau;
        {
            half8v m8 = xq[0];
#pragma unroll
            for (int i = 1; i < 9; i++)
                if (i < NS) m8 = __builtin_elementwise_max(m8, xq[i]);
            union { half8v v; half2v h[4]; } u; u.v = m8;
            half2v m2 = __builtin_elementwise_max(
                __builtin_elementwise_max(u.h[0], u.h[1]),
                __builtin_elementwise_max(u.h[2], u.h[3]));
            float mx = fmaxf((float)m2[0], (float)m2[1]);
            mx = rowmax16(mx);
            tau = mx - 1.0f;            // g(tau0) >= 1 -> monotone Newton
        }

        // ---- Newton, early-exit, ZERO barriers ----
        const float nact = (float)(8 * NS);
#pragma unroll 1
        for (int it = 0; it < 12; it++) {
            const _Float16 th = (_Float16)tau;
            const float tf = (float)th;
            const half8v t8 = {th, th, th, th, th, th, th, th};
            float m1a = 0.f, m1b = 0.f, m2a = 0.f, m2b = 0.f;
#pragma unroll
            for (int i = 0; i < 9; i++) {
                if (i < NS) {
                    union { half8v v; half2v h[4]; } u;
                    u.v = __builtin_elementwise_max(xq[i], t8);
                    m1a = fdot2f(u.h[0], one2, m1a);
                    m2a = fdot2f(u.h[0], u.h[0], m2a);
                    m1b = fdot2f(u.h[1], one2, m1b);
                    m2b = fdot2f(u.h[1], u.h[1], m2b);
                    m1a = fdot2f(u.h[2], one2, m1a);
                    m2a = fdot2f(u.h[2], u.h[2], m2a);
                    m1b = fdot2f(u.h[3], one2, m1b);
                    m2b = fdot2f(u.h[3], u.h[3], m2b);
                }
            }
            const float M1 = m1a + m1b, M2 = m2a + m2b;
            float s1 = fmaf(-nact, tf, M1);
            float s2 = fmaf(tf, fmaf(nact, tf, -2.f * M1), M2);
            s1 = rowsum16(s1);
            s2 = rowsum16(s2);
            const float delta = (s2 - 1.0f) / (2.0f * fmaxf(s1, 1e-4f));
            tau += delta;
            if (__all(fabsf(delta) < 2.5e-4f)) break;
        }

        // ---- P = relu(x-tau)^2 in-place + PV (4-way acc split) ----
        const _Float16 th = (_Float16)tau;
        const half8v t8 = {th, th, th, th, th, th, th, th};
        const half8v z8 = (half8v)(_Float16)0.f;
        floatx4 oa0 = (floatx4)0.f, oa1 = (floatx4)0.f;
        floatx4 oa2 = (floatx4)0.f, oa3 = (floatx4)0.f;
#pragma unroll
        for (int s = 0; s < 8; s++) {
            if (s < NS) {
                half8v dp = __builtin_elementwise_max(xq[s] - t8, z8);
                const int b = 16 * s + lc;
                const int p = b ^ ((b >> 3) & 7) ^ (R & 7);
                *(half8v*)&Plds[R * 1024 + p * 8] = dp * dp;
            }
        }
        __syncthreads();
        __builtin_amdgcn_s_setprio(1);
#pragma unroll
        for (int kt = 0; kt < 32; kt++) {
            if (kt < NT) {
                const int b = kt * 4 + lg;
                const int p = b ^ ((b >> 3) & 7) ^ (lc & 7);
                half8v af = *(const half8v*)&Plds[lc * 1024 + p * 8];
                half8v bf = *(const half8v*)(vp + kt * 32);
                if ((kt & 3) == 0)      oa0 = mfma_f16(af, bf, oa0);
                else if ((kt & 3) == 1) oa1 = mfma_f16(af, bf, oa1);
                else if ((kt & 3) == 2) oa2 = mfma_f16(af, bf, oa2);
                else                    oa3 = mfma_f16(af, bf, oa3);
            }
        }
        __builtin_amdgcn_s_setprio(0);
        if (NS > 8) {                   // slot-8 P via chunk, PV tiles 32..35
            __syncthreads();
            {
                half8v dp = __builtin_elementwise_max(xq[8] - t8, z8);
                const int b = lc;
                const int p = b ^ ((b >> 3) & 7) ^ (R & 7);
                *(half8v*)&Plds[R * 1024 + p * 8] = dp * dp;
            }
            __syncthreads();
            const u16* vph = vp + 1024;
#pragma unroll
            for (int kt2 = 0; kt2 < 4; kt2++) {
                if (32 + kt2 < NT) {
                    const int b = kt2 * 4 + lg;
                    const int p = b ^ ((b >> 3) & 7) ^ (lc & 7);
                    half8v af = *(const half8v*)&Plds[lc * 1024 + p * 8];
                    half8v bf = *(const half8v*)(vph + kt2 * 32);
                    if ((kt2 & 3) == 0)      oa0 = mfma_f16(af, bf, oa0);
                    else if ((kt2 & 3) == 1) oa1 = mfma_f16(af, bf, oa1);
                    else if ((kt2 & 3) == 2) oa2 = mfma_f16(af, bf, oa2);
                    else                     oa3 = mfma_f16(af, bf, oa3);
                }
            }
        }
        const floatx4 oacc = (oa0 + oa1) + (oa2 + oa3);
#pragma unroll
        for (int r = 0; r < 4; r++)
            att[(size_t)(q0 + lg * 4 + r) * D + hh * HD + w * 16 + lc] =
                f2bu(oacc[r]);
    } else {
        // =================== big path (nk > 1152 fallback) ===================
        half4v sc[32];
        {
            __builtin_amdgcn_s_setprio(1);
#pragma unroll
            for (int T = 0; T < 32; T++) {
                const int g = 4 * T + w;
                if (g * 16 < nk) {
                    const u16* kp = kbase + (size_t)(g * 16 + lc) * D;
                    floatx4 a = (floatx4)0.f;
                    a = mfma_f16(*(const half8v*)kp,        bq0, a);
                    a = mfma_f16(*(const half8v*)(kp + 32), bq1, a);
                    const int kb0 = g * 16 + lg * 4;
                    half2v p01 = pkrtz(kb0 + 0 < nk ? a[0] * 0.0625f : -30000.f,
                                       kb0 + 1 < nk ? a[1] * 0.0625f : -30000.f);
                    half2v p23 = pkrtz(kb0 + 2 < nk ? a[2] * 0.0625f : -30000.f,
                                       kb0 + 3 < nk ? a[3] * 0.0625f : -30000.f);
                    sc[T] = __builtin_shufflevector(p01, p23, 0, 1, 2, 3);
                } else {
                    sc[T] = NEG4;
                }
            }
            __builtin_amdgcn_s_setprio(0);
        }

        half8v xq[16];
        {
#pragma unroll
            for (int T = 0; T < 16; T++) {
                const int g  = 4 * T + w;
                const int kl = g * 16 + lg * 4;
                const int b  = kl >> 3;
                const int p  = b ^ ((b >> 3) & 7) ^ (lc & 7);
                *(half4v*)&Plds[lc * 1024 + p * 8 + (lg & 1) * 4] = sc[T];
            }
            __syncthreads();
#pragma unroll
            for (int s = 0; s < 8; s++) {
                if (s < NS) {
                    const int b = 16 * s + lc;
                    const int p = b ^ ((b >> 3) & 7) ^ (R & 7);
                    xq[s] = *(const half8v*)&Plds[R * 1024 + p * 8];
                }
            }
            __syncthreads();
#pragma unroll
            for (int T = 16; T < 32; T++) {
                const int g  = 4 * T + w;
                const int kl = g * 16 + lg * 4 - 1024;
                const int b  = kl >> 3;
                const int p  = b ^ ((b >> 3) & 7) ^ (lc & 7);
                *(half4v*)&Plds[lc * 1024 + p * 8 + (lg & 1) * 4] = sc[T];
            }
            __syncthreads();
#pragma unroll
            for (int s = 0; s < 8; s++) {
                const int j = 8 + s;
                if (j < NS) {
                    const int b = 16 * s + lc;
                    const int p = b ^ ((b >> 3) & 7) ^ (R & 7);
                    xq[j] = *(const half8v*)&Plds[R * 1024 + p * 8];
                }
            }
        }

        float tau;
        {
            half8v m8 = xq[0];
#pragma unroll
            for (int i = 1; i < 16; i++)
                if (i < NS) m8 = __builtin_elementwise_max(m8, xq[i]);
            union { half8v v; half2v h[4]; } u; u.v = m8;
            half2v m2 = __builtin_elementwise_max(
                __builtin_elementwise_max(u.h[0], u.h[1]),
                __builtin_elementwise_max(u.h[2], u.h[3]));
            float mx = fmaxf((float)m2[0], (float)m2[1]);
            mx = rowmax16(mx);
            tau = mx - 1.0f;
        }

        const float nact = (float)(8 * NS);
#pragma unroll 1
        for (int it = 0; it < 12; it++) {
            const _Float16 th = (_Float16)tau;
            const float tf = (float)th;
            const half8v t8 = {th, th, th, th, th, th, th, th};
            float m1a = 0.f, m1b = 0.f, m2a = 0.f, m2b = 0.f;
#pragma unroll
            for (int i = 0; i < 16; i++) {
                if (i < NS) {
                    union { half8v v; half2v h[4]; } u;
                    u.v = __builtin_elementwise_max(xq[i], t8);
                    m1a = fdot2f(u.h[0], one2, m1a);
                    m2a = fdot2f(u.h[0], u.h[0], m2a);
                    m1b = fdot2f(u.h[1], one2, m1b);
                    m2b = fdot2f(u.h[1], u.h[1], m2b);
                    m1a = fdot2f(u.h[2], one2, m1a);
                    m2a = fdot2f(u.h[2], u.h[2], m2a);
                    m1b = fdot2f(u.h[3], one2, m1b);
                    m2b = fdot2f(u.h[3], u.h[3], m2b);
                }
            }
            const float M1 = m1a + m1b, M2 = m2a + m2b;
            float s1 = fmaf(-nact, tf, M1);
            float s2 = fmaf(tf, fmaf(nact, tf, -2.f * M1), M2);
            s1 = rowsum16(s1);
            s2 = rowsum16(s2);
            const float delta = (s2 - 1.0f) / (2.0f * fmaxf(s1, 1e-4f));
            tau += delta;
            if (__all(fabsf(delta) < 2.5e-4f)) break;
        }

        const _Float16 th = (_Float16)tau;
        const half8v t8 = {th, th, th, th, th, th, th, th};
        const half8v z8 = (half8v)(_Float16)0.f;
        floatx4 oa0 = (floatx4)0.f, oa1 = (floatx4)0.f;
        floatx4 oa2 = (floatx4)0.f, oa3 = (floatx4)0.f;
#pragma unroll
        for (int s = 0; s < 8; s++) {
            if (s < NS) {
                half8v dp = __builtin_elementwise_max(xq[s] - t8, z8);
                const int b = 16 * s + lc;
                const int p = b ^ ((b >> 3) & 7) ^ (R & 7);
                *(half8v*)&Plds[R * 1024 + p * 8] = dp * dp;
            }
        }
        __syncthreads();
        __builtin_amdgcn_s_setprio(1);
#pragma unroll
        for (int kt = 0; kt < 32; kt++) {
            if (kt < NT) {
                const int b = kt * 4 + lg;
                const int p = b ^ ((b >> 3) & 7) ^ (lc & 7);
                half8v af = *(const half8v*)&Plds[lc * 1024 + p * 8];
                half8v bf = *(const half8v*)(vp + kt * 32);
                if ((kt & 3) == 0)      oa0 = mfma_f16(af, bf, oa0);
                else if ((kt & 3) == 1) oa1 = mfma_f16(af, bf, oa1);
                else if ((kt & 3) == 2) oa2 = mfma_f16(af, bf, oa2);
                else                    oa3 = mfma_f16(af, bf, oa3);
            }
        }
        __builtin_amdgcn_s_setprio(0);
        {
            __syncthreads();
#pragma unroll
            for (int s = 0; s < 8; s++) {
                const int j = 8 + s;
                if (j < NS) {
                    half8v dp = __builtin_elementwise_max(xq[j] - t8, z8);
                    const int b = 16 * s + lc;
                    const int p = b ^ ((b >> 3) & 7) ^ (R & 7);
                    *(half8v*)&Plds[R * 1024 + p * 8] = dp * dp;
                }
            }
            __syncthreads();
            const u16* vph = vp + 1024;
            __builtin_amdgcn_s_setprio(1);
#pragma unroll
            for (int kt = 0; kt < 32; kt++) {
                if (32 + kt < NT) {
                    const int b = kt * 4 + lg;
                    const int p = b ^ ((b >> 3) & 7) ^ (lc & 7);
                    half8v af = *(const half8v*)&Plds[lc * 1024 + p * 8];
                    half8v bf = *(const half8v*)(vph + kt * 32);
                    if ((kt & 3) == 0)      oa0 = mfma_f16(af, bf, oa0);
                    else if ((kt & 3) == 1) oa1 = mfma_f16(af, bf, oa1);
                    else if ((kt & 3) == 2) oa2 = mfma_f16(af, bf, oa2);
                    else                    oa3 = mfma_f16(af, bf, oa3);
                }
            }
            __builtin_amdgcn_s_setprio(0);
        }
        const floatx4 oacc = (oa0 + oa1) + (oa2 + oa3);
#pragma unroll
        for (int r = 0; r < 4; r++)
            att[(size_t)(q0 + lg * 4 + r) * D + hh * HD + w * 16 + lc] =
                f2bu(oacc[r]);
    }
}

// ---------------- host side ---------------------------------------------------
extern "C" void kernel_launch(void* const* d_in, const int* in_sizes, int n_in,
                              void* d_out, int out_size, void* d_ws, size_t ws_size,
                              hipStream_t stream)
{
    const float* inp  = (const float*)d_in[0];
    const int*   mask = (const int*)d_in[1];
    const float* wq   = (const float*)d_in[2];
    const float* bq   = (const float*)d_in[3];
    const float* wk   = (const float*)d_in[4];
    const float* bk   = (const float*)d_in[5];
    const float* wv   = (const float*)d_in[6];
    const float* bv   = (const float*)d_in[7];
    const float* wo   = (const float*)d_in[8];
    const float* bo   = (const float*)d_in[9];
    const float* ln1a = (const float*)d_in[10];
    const float* ln1b = (const float*)d_in[11];
    const float* w1   = (const float*)d_in[12];
    const float* b1   = (const float*)d_in[13];
    const float* w2   = (const float*)d_in[14];
    const float* b2   = (const float*)d_in[15];
    const float* ln2a = (const float*)d_in[16];
    const float* ln2b = (const float*)d_in[17];

    const size_t MB = 1u << 20;
    char* w = (char*)d_ws;
    // 32 MB overlay (16-bit bufs unless noted):
    //  [0,8):  wqkvb(6MB) -> w1b (after QKV) -> w2b (after FFN1)
    //  [8,12): x1 -> att -> x2   (bf16)
    //  [12,16): qb_ (f16) -> yb (bf16)
    //  [16,20): kb_ (f16)  \
    //  [20,24): vTb (f16)   > dead after attn -> hb [16,32)
    //  [24,26): wob (bf16) /  (dead after WO, before FFN1 writes hb)
    //  [26, 26MB+8KB+4): newpos int[2048] + nk  (dead before FFN1 writes hb)
    u16* wqkvb = (u16*)(w + 0 * MB);
    u16* w1b   = (u16*)(w + 0 * MB);
    u16* w2b   = (u16*)(w + 0 * MB);
    u16* x1    = (u16*)(w + 8 * MB);
    u16* att   = x1;
    u16* x2    = x1;
    u16* qb_   = (u16*)(w + 12 * MB);
    u16* yb    = (u16*)(w + 12 * MB);
    u16* kb_   = (u16*)(w + 16 * MB);
    u16* vTb   = (u16*)(w + 20 * MB);
    u16* wob   = (u16*)(w + 24 * MB);
    u16* hb    = (u16*)(w + 16 * MB);
    int* np    = (int*)(w + 26 * MB);
    int* nkbuf = np + 2048;
    float* outF = (float*)d_out;

    // 0. prep: scan + wq/wk/wv/wo conversions (was 5 dispatches)
    prep_kernel<<<4097, 256, 0, stream>>>(mask, np, nkbuf, wq, wk, wv, wo,
                                          wqkvb, wob);
    // 1. LN1 -> bf16
    ln_kernel<float><<<S, 256, 0, stream>>>(inp, ln1a, ln1b, x1);
    // 2. fused QKV projection -> f16 Q [S,D]; K [S,D], V^T [D,S] permuted
    gemm_qkv<<<dim3(3 * D / 128, S / 128), 256, 0, stream>>>(
        x1, wqkvb, bq, bk, bv, np, qb_, kb_, vTb);
    // 3. unified attention (small/big internal) + cvt-w1 tail blocks
    //    (wqkvb dead after QKV -> w1b target free; cvt hidden in attn shadow)
    attn_cvt<<<2048 + 4096, 256, 0, stream>>>(qb_, kb_, vTb, nkbuf, att,
                                              w1, w1b);
    // 4. WO projection + residual(inp fp32) -> yb bf16  (256 blocks)
    gemm_mfma64<1, 1><<<dim3(D / 64, S / 128), 256, 0, stream>>>(
        att, wob, bo, inp, yb, S, D, D);
    // 5. LN2 -> x2 (att dead)
    ln_kernel<u16><<<S, 256, 0, stream>>>(yb, ln2a, ln2b, x2);
    // 6. FFN1 (+ReLU) -> hb bf16 (kb_/vTb/wob/np dead)
    gemm_mfma<1, true, 0><<<dim3(DFF / 128, S / 128), 256, 0, stream>>>(
        x2, w1b, b1, nullptr, hb, S, DFF, D);
    // 7. convert w2 (w1b dead; cannot overlap: w1b/w2b share [0,8) and hb
    //    fills [16,32))
    cvt_kernel<<<4096, 256, 0, stream>>>(w2, w2b, (DFF * D) / 4);
    // 8. FFN2 + residual(yb bf16) -> fp32 out  (256 blocks)
    gemm_mfma64<0, 2><<<dim3(D / 64, S / 128), 256, 0, stream>>>(
        hb, w2b, b2, yb, outF, S, D, DFF);
}

// Round 8
// 314.921 us; speedup vs baseline: 1.1425x; 1.0292x over previous
//
#include <hip/hip_runtime.h>
#include <hip/hip_bf16.h>

// Problem dims (fixed by setup_inputs)
#define S   2048
#define D   1024
#define DFF 4096
#define NH  16
#define HD  64

typedef unsigned short u16;
typedef unsigned int   u32;
typedef __attribute__((ext_vector_type(8))) short      short8;  // 8 bf16
typedef __attribute__((ext_vector_type(4))) float      floatx4; // MFMA C/D
typedef __attribute__((ext_vector_type(2))) _Float16   half2v;
typedef __attribute__((ext_vector_type(4))) _Float16   half4v;
typedef __attribute__((ext_vector_type(8))) _Float16   half8v;

__device__ __forceinline__ float bu2f(u16 u) {
    union { u32 i; float f; } x; x.i = ((u32)u) << 16; return x.f;
}
__device__ __forceinline__ u16 f2bu(float f) {
    __hip_bfloat16 h = __float2bfloat16(f);
    return *(u16*)&h;
}
__device__ __forceinline__ u16 f2h(float f) {
    _Float16 h = (_Float16)f; return *(u16*)&h;
}
__device__ __forceinline__ float ldf(const float* p) { return *p; }
__device__ __forceinline__ float ldf(const u16* p)   { return bu2f(*p); }

// cvt_pkrtz returns __fp16x2; bit-cast to our _Float16x2 (same 32-bit reg)
__device__ __forceinline__ half2v pkrtz(float a, float b) {
    auto v = __builtin_amdgcn_cvt_pkrtz(a, b);
    union { decltype(v) i; half2v o; } u; u.i = v; return u.o;
}

__device__ __forceinline__ floatx4 mfma_f16(half8v a, half8v b, floatx4 c) {
    return __builtin_amdgcn_mfma_f32_16x16x32_f16(a, b, c, 0, 0, 0);
}
__device__ __forceinline__ float fdot2f(half2v a, half2v b, float c) {
#if __has_builtin(__builtin_amdgcn_fdot2)
    return __builtin_amdgcn_fdot2(a, b, c, false);
#else
    return c + (float)a[0] * (float)b[0] + (float)a[1] * (float)b[1];
#endif
}

// ---- DPP 16-lane row reductions (VALU-speed, replaces ds_swizzle chains) ----
template <int K>
__device__ __forceinline__ float ror16f(float v) {
    int s = __builtin_bit_cast(int, v);
    int r = __builtin_amdgcn_update_dpp(s, s, 0x120 | K, 0xF, 0xF, false);
    return __builtin_bit_cast(float, r);
}
__device__ __forceinline__ float rowsum16(float v) {
    v += ror16f<1>(v);
    v += ror16f<2>(v);
    v += ror16f<4>(v);
    v += ror16f<8>(v);
    return v;
}
__device__ __forceinline__ float rowmax16(float v) {
    v = fmaxf(v, ror16f<1>(v));
    v = fmaxf(v, ror16f<2>(v));
    v = fmaxf(v, ror16f<4>(v));
    v = fmaxf(v, ror16f<8>(v));
    return v;
}

// async global->LDS, 16B per lane, lands at ldsbase + lane*16
__device__ __forceinline__ void async16(const void* g, void* l) {
    __builtin_amdgcn_global_load_lds(
        (const __attribute__((address_space(1))) u32*)g,
        (__attribute__((address_space(3))) u32*)l, 16, 0, 0);
}

// pipeline primitives (counted vmcnt, raw barrier; rule #18: sched_barrier
// after every inline-asm wait)
#define WAITV(N) asm volatile("s_waitcnt vmcnt(" N ")" ::: "memory")
#define WAITL()  asm volatile("s_waitcnt lgkmcnt(0)" ::: "memory")
#define SBAR()   __builtin_amdgcn_s_barrier()
#define SCHED0() __builtin_amdgcn_sched_barrier(0)

// ---------------- fp32 -> bf16 bulk convert (weights) ------------------------
__global__ __launch_bounds__(256)
void cvt_kernel(const float* __restrict__ in, u16* __restrict__ out, int n4)
{
    int i = blockIdx.x * 256 + threadIdx.x;
    if (i < n4) {
        float4 v = ((const float4*)in)[i];
        ushort4 s;
        s.x = f2bu(v.x); s.y = f2bu(v.y); s.z = f2bu(v.z); s.w = f2bu(v.w);
        ((ushort4*)out)[i] = s;
    }
}

// ---------------- prep: scan + cvt wq/wk/wv/wo + LN1 + (opt) cvt w2 ----------
// R8: one dispatch for all independent prologue work:
//  block 0:                scan (newpos + nk)
//  blocks [1, 4096]:       cvt wq/wk/wv/wo
//  blocks [4097, 6144]:    LN1 (2048 rows)
//  blocks [6145, 10240]:   cvt w2 (only if grid extended; host decides on
//                          ws_size >= 40MB so w2b can live at [32,40))
__global__ __launch_bounds__(256)
void prep_kernel(const int* __restrict__ mask, int* __restrict__ newpos,
                 int* __restrict__ nkbuf,
                 const float* __restrict__ wq, const float* __restrict__ wk,
                 const float* __restrict__ wv, const float* __restrict__ wo,
                 u16* __restrict__ wqkvb, u16* __restrict__ wob,
                 const float* __restrict__ inp, const float* __restrict__ ln1a,
                 const float* __restrict__ ln1b, u16* __restrict__ x1,
                 const float* __restrict__ w2, u16* __restrict__ w2dst)
{
    const int blk = blockIdx.x;
    const int t = threadIdx.x;
    if (blk == 0) {
        __shared__ int ps[256];
        int loc[8];
        int s = 0;
#pragma unroll
        for (int j = 0; j < 8; j++) {
            loc[j] = s;
            s += (mask[t * 8 + j] != 0);
        }
        ps[t] = s;
        __syncthreads();
        for (int off = 1; off < 256; off <<= 1) {
            int v = (t >= off) ? ps[t - off] : 0;
            __syncthreads();
            ps[t] += v;
            __syncthreads();
        }
        const int total = ps[255];                 // nk
        const int base = t ? ps[t - 1] : 0;
#pragma unroll
        for (int j = 0; j < 8; j++) {
            const int gi = t * 8 + j;
            const int up = base + loc[j];          // unmasked rank
            newpos[gi] = mask[gi] ? up : (total + gi - up);
        }
        if (t == 0) nkbuf[0] = total;
    } else if (blk <= 4096) {
        int cb = blk - 1;                          // 0..4095, 1024 per weight
        const float* src;
        u16* dst;
        if (cb < 1024)      { src = wq; dst = wqkvb; }
        else if (cb < 2048) { src = wk; dst = wqkvb + 1024 * 1024; cb -= 1024; }
        else if (cb < 3072) { src = wv; dst = wqkvb + 2 * 1024 * 1024; cb -= 2048; }
        else                { src = wo; dst = wob; cb -= 3072; }
        const int i = cb * 256 + t;                // < (D*D)/4 = 262144
        float4 v = ((const float4*)src)[i];
        ushort4 sv;
        sv.x = f2bu(v.x); sv.y = f2bu(v.y); sv.z = f2bu(v.z); sv.w = f2bu(v.w);
        ((ushort4*)dst)[i] = sv;
    } else if (blk <= 6144) {
        // ---- LN1 row ----
        const int rrow = blk - 4097;
        const float* x = inp + (size_t)rrow * D;
        float v[4];
        float s = 0.f, ss = 0.f;
#pragma unroll
        for (int j = 0; j < 4; j++) {
            float val = x[t + 256 * j];
            v[j] = val; s += val; ss = fmaf(val, val, ss);
        }
#pragma unroll
        for (int off = 32; off >= 1; off >>= 1) {
            s  += __shfl_down(s,  off, 64);
            ss += __shfl_down(ss, off, 64);
        }
        __shared__ float red[10];
        const int wave = t >> 6, lane = t & 63;
        if (lane == 0) { red[wave] = s; red[4 + wave] = ss; }
        __syncthreads();
        if (t == 0) {
            float S1 = red[0] + red[1] + red[2] + red[3];
            float S2 = red[4] + red[5] + red[6] + red[7];
            float mu = S1 / (float)D;
            float var = (S2 - (float)D * mu * mu) / (float)(D - 1);  // ddof=1
            float sig = sqrtf(fmaxf(var, 0.f)) + 1e-6f;              // eps
            red[8] = mu; red[9] = 1.f / sig;
        }
        __syncthreads();
        const float mu = red[8], rs = red[9];
#pragma unroll
        for (int j = 0; j < 4; j++) {
            int c = t + 256 * j;
            x1[(size_t)rrow * D + c] = f2bu((v[j] - mu) * rs * ln1a[c] + ln1b[c]);
        }
    } else {
        // ---- early w2 convert (only launched when workspace permits) ----
        const int i = (blk - 6145) * 256 + t;      // < (DFF*D)/4 = 1048576
        float4 v = ((const float4*)w2)[i];
        ushort4 sv;
        sv.x = f2bu(v.x); sv.y = f2bu(v.y); sv.z = f2bu(v.z); sv.w = f2bu(v.w);
        ((ushort4*)w2dst)[i] = sv;
    }
}

// ---------------- LayerNorm: one block per row, D=1024, 256 threads ----------
template <typename T>
__global__ __launch_bounds__(256, 4)
void ln_kernel(const T* __restrict__ in, const float* __restrict__ ga,
               const float* __restrict__ gb, u16* __restrict__ out)
{
    const int row = blockIdx.x;
    const int t = threadIdx.x;
    const T* x = in + (size_t)row * D;
    float v[4];
    float s = 0.f, ss = 0.f;
#pragma unroll
    for (int j = 0; j < 4; j++) {
        float val = ldf(x + t + 256 * j);
        v[j] = val; s += val; ss = fmaf(val, val, ss);
    }
#pragma unroll
    for (int off = 32; off >= 1; off >>= 1) {
        s  += __shfl_down(s,  off, 64);
        ss += __shfl_down(ss, off, 64);
    }
    __shared__ float red[10];
    const int wave = t >> 6, lane = t & 63;
    if (lane == 0) { red[wave] = s; red[4 + wave] = ss; }
    __syncthreads();
    if (t == 0) {
        float S1 = red[0] + red[1] + red[2] + red[3];
        float S2 = red[4] + red[5] + red[6] + red[7];
        float mu = S1 / (float)D;
        float var = (S2 - (float)D * mu * mu) / (float)(D - 1);  // ddof=1
        float sig = sqrtf(fmaxf(var, 0.f)) + 1e-6f;              // eps on sigma
        red[8] = mu; red[9] = 1.f / sig;
    }
    __syncthreads();
    const float mu = red[8], rs = red[9];
#pragma unroll
    for (int j = 0; j < 4; j++) {
        int c = t + 256 * j;
        out[(size_t)row * D + c] = f2bu((v[j] - mu) * rs * ga[c] + gb[c]);
    }
}

// ======================= MFMA GEMM core (128x128 tile) =======================
// 3-buffer, depth-2 global_load_lds pipeline (T3+T4 minimum form).
// Never vmcnt(0) in the main loop; tail peels immediates 4 -> 0.
#define GEMM_CORE(A_, B_, K_)                                                   \
    __shared__ u16 As[3 * 128 * 32];                                            \
    __shared__ u16 Bs[3 * 128 * 32];                                            \
    const int t = threadIdx.x;                                                  \
    const int w = t >> 6, l = t & 63;                                           \
    const int m0 = blockIdx.y * 128, n0 = blockIdx.x * 128;                     \
    const int qk = l >> 4, col = l & 15;                                        \
    const int wm = (w & 1) * 64, wn = (w >> 1) * 64;                            \
    const int sr  = l >> 2;                                                     \
    const int sq  = l & 3;                                                      \
    const int row = w * 16 + sr;                                                \
    const int gq  = sq ^ ((row >> 1) & 3);                                      \
    const u16* Ap = A_ + (size_t)(m0 + row) * K_ + gq * 8;                      \
    const u16* Bp = B_ + (size_t)(n0 + row) * K_ + gq * 8;                      \
    u16* AsW = As + w * 16 * 32;                                                \
    u16* BsW = Bs + w * 16 * 32;                                                \
    const int mloc = wm + col, nloc = wn + col;                                 \
    const int aoff = mloc * 32 + (qk ^ ((mloc >> 1) & 3)) * 8;                  \
    const int boff = nloc * 32 + (qk ^ ((nloc >> 1) & 3)) * 8;                  \
    floatx4 acc[4][4];                                                          \
    _Pragma("unroll")                                                           \
    for (int i = 0; i < 4; i++)                                                 \
        _Pragma("unroll")                                                       \
        for (int j = 0; j < 4; j++) acc[i][j] = (floatx4)0.f;                   \
    const int NT_ = K_ / 32;                                                    \
    _Pragma("unroll")                                                           \
    for (int s = 0; s < 3; s++) {                                               \
        async16(Ap,                   AsW + s * 4096);                          \
        async16(Ap + (size_t)64 * K_, AsW + s * 4096 + 64 * 32);                \
        async16(Bp,                   BsW + s * 4096);                          \
        async16(Bp + (size_t)64 * K_, BsW + s * 4096 + 64 * 32);                \
        Ap += 32; Bp += 32;                                                     \
    }                                                                           \
    WAITV("8"); SCHED0(); SBAR();                                               \
    int cur = 0;                                                                \
    for (int t0 = 0; t0 + 3 < NT_; ++t0) {                                      \
        short8 a[4], b[4];                                                      \
        const u16* aB = As + cur * 4096 + aoff;                                 \
        const u16* bB = Bs + cur * 4096 + boff;                                 \
        _Pragma("unroll")                                                       \
        for (int i = 0; i < 4; i++) a[i] = *(const short8*)(aB + i * 16 * 32);  \
        _Pragma("unroll")                                                       \
        for (int j = 0; j < 4; j++) b[j] = *(const short8*)(bB + j * 16 * 32);  \
        WAITL(); SCHED0(); SBAR();                                              \
        async16(Ap,                   AsW + cur * 4096);                        \
        async16(Ap + (size_t)64 * K_, AsW + cur * 4096 + 64 * 32);              \
        async16(Bp,                   BsW + cur * 4096);                        \
        async16(Bp + (size_t)64 * K_, BsW + cur * 4096 + 64 * 32);              \
        Ap += 32; Bp += 32;                                                     \
        _Pragma("unroll")                                                       \
        for (int i = 0; i < 4; i++)                                             \
            _Pragma("unroll")                                                   \
            for (int j = 0; j < 4; j++)                                         \
                acc[i][j] = __builtin_amdgcn_mfma_f32_16x16x32_bf16(            \
                    a[i], b[j], acc[i][j], 0, 0, 0);                            \
        WAITV("8"); SCHED0(); SBAR();                                           \
        cur = cur + 1; if (cur == 3) cur = 0;                                   \
    }                                                                           \
    _Pragma("unroll")                                                           \
    for (int tail = 0; tail < 3; tail++) {                                      \
        short8 a[4], b[4];                                                      \
        const u16* aB = As + cur * 4096 + aoff;                                 \
        const u16* bB = Bs + cur * 4096 + boff;                                 \
        _Pragma("unroll")                                                       \
        for (int i = 0; i < 4; i++) a[i] = *(const short8*)(aB + i * 16 * 32);  \
        _Pragma("unroll")                                                       \
        for (int j = 0; j < 4; j++) b[j] = *(const short8*)(bB + j * 16 * 32);  \
        _Pragma("unroll")                                                       \
        for (int i = 0; i < 4; i++)                                             \
            _Pragma("unroll")                                                   \
            for (int j = 0; j < 4; j++)                                         \
                acc[i][j] = __builtin_amdgcn_mfma_f32_16x16x32_bf16(            \
                    a[i], b[j], acc[i][j], 0, 0, 0);                            \
        if (tail == 0) { WAITV("4"); SCHED0(); SBAR(); }                        \
        if (tail == 1) { WAITV("0"); SCHED0(); SBAR(); }                        \
        cur = cur + 1; if (cur == 3) cur = 0;                                   \
    }

// ---- generic GEMM 128x128 (+bias/relu/res), OMODE 0 f32 / 1 bf16 ------------
template <int OMODE, bool RELU, int RES>
__global__ __launch_bounds__(256, 2)
void gemm_mfma(const u16* __restrict__ A, const u16* __restrict__ B,
               const float* __restrict__ bias, const void* __restrict__ res,
               void* __restrict__ Cout, int M, int N, int K)
{
    GEMM_CORE(A, B, K)
#pragma unroll
    for (int j = 0; j < 4; j++) {
        const int n = n0 + wn + j * 16 + col;
        const float bn = bias[n];
#pragma unroll
        for (int i = 0; i < 4; i++) {
#pragma unroll
            for (int r = 0; r < 4; r++) {
                const int m = m0 + wm + i * 16 + qk * 4 + r;
                float v = acc[i][j][r] + bn;
                if (RELU) v = fmaxf(v, 0.f);
                if (RES == 1) v += ((const float*)res)[(size_t)m * N + n];
                if (RES == 2) v += bu2f(((const u16*)res)[(size_t)m * N + n]);
                if (OMODE == 0) ((float*)Cout)[(size_t)m * N + n] = v;
                if (OMODE == 1) ((u16*)Cout)[(size_t)m * N + n] = f2bu(v);
            }
        }
    }
}

// ---- fused QKV GEMM (128x128): f16 Q [S,D]; K,V^T written PERMUTED by np ----
__global__ __launch_bounds__(256, 2)
void gemm_qkv(const u16* __restrict__ A, const u16* __restrict__ B,
              const float* __restrict__ bq, const float* __restrict__ bk,
              const float* __restrict__ bv, const int* __restrict__ np,
              u16* __restrict__ outQ, u16* __restrict__ outK,
              u16* __restrict__ outVT)
{
    const int K = D;
    GEMM_CORE(A, B, K)
    const int seg   = n0 >> 10;
    const int nbase = n0 & 1023;
    const float* bs = (seg == 0) ? bq : (seg == 1) ? bk : bv;
    int npm[4][4];
    if (seg != 0) {
#pragma unroll
        for (int i = 0; i < 4; i++)
#pragma unroll
            for (int r = 0; r < 4; r++)
                npm[i][r] = np[m0 + wm + i * 16 + qk * 4 + r];
    }
#pragma unroll
    for (int j = 0; j < 4; j++) {
        const int nl = nbase + wn + j * 16 + col;
        const float bn = bs[nl];
#pragma unroll
        for (int i = 0; i < 4; i++) {
#pragma unroll
            for (int r = 0; r < 4; r++) {
                const int m = m0 + wm + i * 16 + qk * 4 + r;
                float v = acc[i][j][r] + bn;
                if (seg == 0)      outQ [(size_t)m * D + nl]          = f2h(v);
                else if (seg == 1) outK [(size_t)npm[i][r] * D + nl]  = f2h(v);
                else               outVT[(size_t)nl * S + npm[i][r]]  = f2h(v);
            }
        }
    }
}

// ---- 64x64-tile GEMM (R8): 512 blocks for N=1024 outputs -> 2 blocks/CU -----
// WO and FFN2 previously ran 256 blocks = 1 block/CU = 1 wave/SIMD: barrier
// and load stalls fully exposed. 64x64 doubles resident waves. Same 3-buffer
// depth-2 pipeline; 2 loads/stage -> vmcnt 4 / 2 / 0.
template <int OMODE, int RES>
__global__ __launch_bounds__(256, 4)
void gemm64(const u16* __restrict__ A, const u16* __restrict__ B,
            const float* __restrict__ bias, const void* __restrict__ res,
            void* __restrict__ Cout, int M, int N, int K)
{
    __shared__ u16 As[3 * 64 * 32];     // 12 KB
    __shared__ u16 Bs[3 * 64 * 32];     // 12 KB
    const int t = threadIdx.x;
    const int w = t >> 6, l = t & 63;
    const int m0 = blockIdx.y * 64, n0 = blockIdx.x * 64;
    const int qk = l >> 4, col = l & 15;
    const int wm = (w & 1) * 32, wn = (w >> 1) * 32;
    const int sr = l >> 2, sq = l & 3;
    const int row = w * 16 + sr;        // 0..63
    const int gq = sq ^ ((row >> 1) & 3);
    const u16* Ap = A + (size_t)(m0 + row) * K + gq * 8;
    const u16* Bp = B + (size_t)(n0 + row) * K + gq * 8;
    u16* AsW = As + w * 16 * 32;
    u16* BsW = Bs + w * 16 * 32;
    const int mloc = wm + col, nloc = wn + col;
    const int aoff = mloc * 32 + (qk ^ ((mloc >> 1) & 3)) * 8;
    const int boff = nloc * 32 + (qk ^ ((nloc >> 1) & 3)) * 8;
    floatx4 acc[2][2];
#pragma unroll
    for (int i = 0; i < 2; i++)
#pragma unroll
        for (int j = 0; j < 2; j++) acc[i][j] = (floatx4)0.f;
    const int NT_ = K / 32;
#pragma unroll
    for (int s = 0; s < 3; s++) {
        async16(Ap, AsW + s * 2048);
        async16(Bp, BsW + s * 2048);
        Ap += 32; Bp += 32;
    }
    WAITV("4"); SCHED0(); SBAR();
    int cur = 0;
    for (int t0 = 0; t0 + 3 < NT_; ++t0) {
        short8 a[2], b[2];
        const u16* aB = As + cur * 2048 + aoff;
        const u16* bB = Bs + cur * 2048 + boff;
#pragma unroll
        for (int i = 0; i < 2; i++) a[i] = *(const short8*)(aB + i * 16 * 32);
#pragma unroll
        for (int j = 0; j < 2; j++) b[j] = *(const short8*)(bB + j * 16 * 32);
        WAITL(); SCHED0(); SBAR();
        async16(Ap, AsW + cur * 2048);
        async16(Bp, BsW + cur * 2048);
        Ap += 32; Bp += 32;
#pragma unroll
        for (int i = 0; i < 2; i++)
#pragma unroll
            for (int j = 0; j < 2; j++)
                acc[i][j] = __builtin_amdgcn_mfma_f32_16x16x32_bf16(
                    a[i], b[j], acc[i][j], 0, 0, 0);
        WAITV("4"); SCHED0(); SBAR();
        cur = cur + 1; if (cur == 3) cur = 0;
    }
#pragma unroll
    for (int tail = 0; tail < 3; tail++) {
        short8 a[2], b[2];
        const u16* aB = As + cur * 2048 + aoff;
        const u16* bB = Bs + cur * 2048 + boff;
#pragma unroll
        for (int i = 0; i < 2; i++) a[i] = *(const short8*)(aB + i * 16 * 32);
#pragma unroll
        for (int j = 0; j < 2; j++) b[j] = *(const short8*)(bB + j * 16 * 32);
#pragma unroll
        for (int i = 0; i < 2; i++)
#pragma unroll
            for (int j = 0; j < 2; j++)
                acc[i][j] = __builtin_amdgcn_mfma_f32_16x16x32_bf16(
                    a[i], b[j], acc[i][j], 0, 0, 0);
        if (tail == 0) { WAITV("2"); SCHED0(); SBAR(); }
        if (tail == 1) { WAITV("0"); SCHED0(); SBAR(); }
        cur = cur + 1; if (cur == 3) cur = 0;
    }
#pragma unroll
    for (int j = 0; j < 2; j++) {
        const int n = n0 + wn + j * 16 + col;
        const float bn = bias[n];
#pragma unroll
        for (int i = 0; i < 2; i++) {
#pragma unroll
            for (int r = 0; r < 4; r++) {
                const int m = m0 + wm + i * 16 + qk * 4 + r;
                float v = acc[i][j][r] + bn;
                if (RES == 1) v += ((const float*)res)[(size_t)m * N + n];
                if (RES == 2) v += bu2f(((const u16*)res)[(size_t)m * N + n]);
                if (OMODE == 0) ((float*)Cout)[(size_t)m * N + n] = v;
                if (OMODE == 1) ((u16*)Cout)[(size_t)m * N + n] = f2bu(v);
            }
        }
    }
}

// =================== unified attention + cvt-w1 tail =========================
// blocks [0,2048): attention, internal small/big switch on nk (block-uniform).
// blocks [2048,6144): cvt of w1 (f32->bf16) backfilling attn's idle CUs.
__global__ __launch_bounds__(256, 3)
void attn_cvt(const u16* __restrict__ qb, const u16* __restrict__ kb,
              const u16* __restrict__ vT, const int* __restrict__ nkbuf,
              u16* __restrict__ att,
              const float* __restrict__ w1src, u16* __restrict__ w1dst)
{
    __shared__ u16 Plds[16 * 1024];     // 32 KB: scores, then P (attn blocks)
    const int blk = blockIdx.x;
    const int t  = threadIdx.x;
    if (blk >= 2048) {                  // ---- cvt-w1 tail blocks ----
        const int i = (blk - 2048) * 256 + t;      // < (DFF*D)/4 = 1048576
        float4 v = ((const float4*)w1src)[i];
        ushort4 sv;
        sv.x = f2bu(v.x); sv.y = f2bu(v.y); sv.z = f2bu(v.z); sv.w = f2bu(v.w);
        ((ushort4*)w1dst)[i] = sv;
        return;
    }
    const int nk = nkbuf[0];            // uniform (scalar load)
    const int NS = (nk + 127) >> 7;     // active 128-key register slots
    const int NT = (nk + 31) >> 5;      // active 32-key PV tiles
    const int hh = blk >> 7;
    const int q0 = (blk & 127) * 16;
    const int w  = __builtin_amdgcn_readfirstlane(t >> 6);   // wave id -> SGPR
    const int l  = t & 63;
    const int lg = l >> 4, lc = l & 15;
    const _Float16 NEG = (_Float16)(-30000.f);
    const half4v NEG4 = {NEG, NEG, NEG, NEG};

    // Q as B-operand: B[n=lc (q-row)][k=lg*8+j]
    const u16* qp = qb + (size_t)(q0 + lc) * D + hh * HD + lg * 8;
    const half8v bq0 = *(const half8v*)qp;
    const half8v bq1 = *(const half8v*)(qp + 32);
    const u16* kbase = kb + hh * HD + lg * 8;
    const int R = 4 * w + lg;
    const half2v one2 = {(_Float16)1.f, (_Float16)1.f};
    const u16* vp = vT + (size_t)(hh * HD + w * 16 + lc) * S + lg * 8;

    if (nk <= 1152) {
        // =================== small path (nk <= 1152; P ~ 1-2e-4) =============
#pragma unroll
        for (int T = 0; T < 16; T++) {
            const int g = 4 * T + w;
            if (g < 8 * NS) {           // tile's slot is active (wave-uniform)
                half4v scv;
                if ((g + 1) * 16 <= nk) {
                    const u16* kp = kbase + (size_t)(g * 16 + lc) * D;
                    floatx4 a = (floatx4)0.f;
                    a = mfma_f16(*(const half8v*)kp,        bq0, a);   // A = K !
                    a = mfma_f16(*(const half8v*)(kp + 32), bq1, a);
                    half2v p01 = pkrtz(a[0] * 0.0625f, a[1] * 0.0625f);
                    half2v p23 = pkrtz(a[2] * 0.0625f, a[3] * 0.0625f);
                    scv = __builtin_shufflevector(p01, p23, 0, 1, 2, 3);
                } else if (g * 16 < nk) {
                    const u16* kp = kbase + (size_t)(g * 16 + lc) * D;
                    floatx4 a = (floatx4)0.f;
                    a = mfma_f16(*(const half8v*)kp,        bq0, a);
                    a = mfma_f16(*(const half8v*)(kp + 32), bq1, a);
                    const int kb0 = g * 16 + lg * 4;
                    half2v p01 = pkrtz(kb0 + 0 < nk ? a[0] * 0.0625f : -30000.f,
                                       kb0 + 1 < nk ? a[1] * 0.0625f : -30000.f);
                    half2v p23 = pkrtz(kb0 + 2 < nk ? a[2] * 0.0625f : -30000.f,
                                       kb0 + 3 < nk ? a[3] * 0.0625f : -30000.f);
                    scv = __builtin_shufflevector(p01, p23, 0, 1, 2, 3);
                } else {
                    scv = NEG4;
                }
                const int kl = g * 16 + lg * 4;
                const int b  = kl >> 3;
                const int p  = b ^ ((b >> 3) & 7) ^ (lc & 7);
                *(half4v*)&Plds[lc * 1024 + p * 8 + (lg & 1) * 4] = scv;
            }
        }
        __syncthreads();

        half8v xq[9];
#pragma unroll
        for (int s = 0; s < 8; s++) {
            if (s < NS) {
                const int b = 16 * s + lc;
                const int p = b ^ ((b >> 3) & 7) ^ (R & 7);
                xq[s] = *(const half8v*)&Plds[R * 1024 + p * 8];
            }
        }
        if (NS > 8) {                   // slot 8: keys [1024,1152) via chunk
            __syncthreads();
#pragma unroll
            for (int T = 16; T < 18; T++) {
                const int g = 4 * T + w;
                half4v scv;
                if ((g + 1) * 16 <= nk) {
                    const u16* kp = kbase + (size_t)(g * 16 + lc) * D;
                    floatx4 a = (floatx4)0.f;
                    a = mfma_f16(*(const half8v*)kp,        bq0, a);
                    a = mfma_f16(*(const half8v*)(kp + 32), bq1, a);
                    half2v p01 = pkrtz(a[0] * 0.0625f, a[1] * 0.0625f);
                    half2v p23 = pkrtz(a[2] * 0.0625f, a[3] * 0.0625f);
                    scv = __builtin_shufflevector(p01, p23, 0, 1, 2, 3);
                } else if (g * 16 < nk) {
                    const u16* kp = kbase + (size_t)(g * 16 + lc) * D;
                    floatx4 a = (floatx4)0.f;
                    a = mfma_f16(*(const half8v*)kp,        bq0, a);
                    a = mfma_f16(*(const half8v*)(kp + 32), bq1, a);
                    const int kb0 = g * 16 + lg * 4;
                    half2v p01 = pkrtz(kb0 + 0 < nk ? a[0] * 0.0625f : -30000.f,
                                       kb0 + 1 < nk ? a[1] * 0.0625f : -30000.f);
                    half2v p23 = pkrtz(kb0 + 2 < nk ? a[2] * 0.0625f : -30000.f,
                                       kb0 + 3 < nk ? a[3] * 0.0625f : -30000.f);
                    scv = __builtin_shufflevector(p01, p23, 0, 1, 2, 3);
                } else {
                    scv = NEG4;
                }
                const int kl = g * 16 + lg * 4 - 1024;   // chunk-local
                const int b  = kl >> 3;
                const int p  = b ^ ((b >> 3) & 7) ^ (lc & 7);
                *(half4v*)&Plds[lc * 1024 + p * 8 + (lg & 1) * 4] = scv;
            }
            __syncthreads();
            {
                const int b = lc;
                const int p = b ^ ((b >> 3) & 7) ^ (R & 7);
                xq[8] = *(const half8v*)&Plds[R * 1024 + p * 8];
            }
        }

        float tau;
        {
            half8v m8 = xq[0];
#pragma unroll
            for (int i = 1; i < 9; i++)
                if (i < NS) m8 = __builtin_elementwise_max(m8, xq[i]);
            union { half8v v; half2v h[4]; } u; u.v = m8;
            half2v m2 = __builtin_elementwise_max(
                __builtin_elementwise_max(u.h[0], u.h[1]),
                __builtin_elementwise_max(u.h[2], u.h[3]));
            float mx = fmaxf((float)m2[0], (float)m2[1]);
            mx = rowmax16(mx);
            tau = mx - 1.0f;            // g(tau0) >= 1 -> monotone Newton
        }

        const float nact = (float)(8 * NS);
#pragma unroll 1
        for (int it = 0; it < 12; it++) {
            const _Float16 th = (_Float16)tau;
            const float tf = (float)th;
            const half8v t8 = {th, th, th, th, th, th, th, th};
            float m1a = 0.f, m1b = 0.f, m2a = 0.f, m2b = 0.f;
#pragma unroll
            for (int i = 0; i < 9; i++) {
                if (i < NS) {
                    union { half8v v; half2v h[4]; } u;
                    u.v = __builtin_elementwise_max(xq[i], t8);
                    m1a = fdot2f(u.h[0], one2, m1a);
                    m2a = fdot2f(u.h[0], u.h[0], m2a);
                    m1b = fdot2f(u.h[1], one2, m1b);
                    m2b = fdot2f(u.h[1], u.h[1], m2b);
                    m1a = fdot2f(u.h[2], one2, m1a);
                    m2a = fdot2f(u.h[2], u.h[2], m2a);
                    m1b = fdot2f(u.h[3], one2, m1b);
                    m2b = fdot2f(u.h[3], u.h[3], m2b);
                }
            }
            const float M1 = m1a + m1b, M2 = m2a + m2b;
            float s1 = fmaf(-nact, tf, M1);
            float s2 = fmaf(tf, fmaf(nact, tf, -2.f * M1), M2);
            s1 = rowsum16(s1);
            s2 = rowsum16(s2);
            const float delta = (s2 - 1.0f) / (2.0f * fmaxf(s1, 1e-4f));
            tau += delta;
            if (__all(fabsf(delta) < 2.5e-4f)) break;
        }

        const _Float16 th = (_Float16)tau;
        const half8v t8 = {th, th, th, th, th, th, th, th};
        const half8v z8 = (half8v)(_Float16)0.f;
        floatx4 oa0 = (floatx4)0.f, oa1 = (floatx4)0.f;
        floatx4 oa2 = (floatx4)0.f, oa3 = (floatx4)0.f;
#pragma unroll
        for (int s = 0; s < 8; s++) {
            if (s < NS) {
                half8v dp = __builtin_elementwise_max(xq[s] - t8, z8);
                const int b = 16 * s + lc;
                const int p = b ^ ((b >> 3) & 7) ^ (R & 7);
                *(half8v*)&Plds[R * 1024 + p * 8] = dp * dp;
            }
        }
        __syncthreads();
        __builtin_amdgcn_s_setprio(1);
#pragma unroll
        for (int kt = 0; kt < 32; kt++) {
            if (kt < NT) {
                const int b = kt * 4 + lg;
                const int p = b ^ ((b >> 3) & 7) ^ (lc & 7);
                half8v af = *(const half8v*)&Plds[lc * 1024 + p * 8];
                half8v bf = *(const half8v*)(vp + kt * 32);
                if ((kt & 3) == 0)      oa0 = mfma_f16(af, bf, oa0);
                else if ((kt & 3) == 1) oa1 = mfma_f16(af, bf, oa1);
                else if ((kt & 3) == 2) oa2 = mfma_f16(af, bf, oa2);
                else                    oa3 = mfma_f16(af, bf, oa3);
            }
        }
        __builtin_amdgcn_s_setprio(0);
        if (NS > 8) {                   // slot-8 P via chunk, PV tiles 32..35
            __syncthreads();
            {
                half8v dp = __builtin_elementwise_max(xq[8] - t8, z8);
                const int b = lc;
                const int p = b ^ ((b >> 3) & 7) ^ (R & 7);
                *(half8v*)&Plds[R * 1024 + p * 8] = dp * dp;
            }
            __syncthreads();
            const u16* vph = vp + 1024;
#pragma unroll
            for (int kt2 = 0; kt2 < 4; kt2++) {
                if (32 + kt2 < NT) {
                    const int b = kt2 * 4 + lg;
                    const int p = b ^ ((b >> 3) & 7) ^ (lc & 7);
                    half8v af = *(const half8v*)&Plds[lc * 1024 + p * 8];
                    half8v bf = *(const half8v*)(vph + kt2 * 32);
                    if ((kt2 & 3) == 0)      oa0 = mfma_f16(af, bf, oa0);
                    else if ((kt2 & 3) == 1) oa1 = mfma_f16(af, bf, oa1);
                    else if ((kt2 & 3) == 2) oa2 = mfma_f16(af, bf, oa2);
                    else                     oa3 = mfma_f16(af, bf, oa3);
                }
            }
        }
        const floatx4 oacc = (oa0 + oa1) + (oa2 + oa3);
#pragma unroll
        for (int r = 0; r < 4; r++)
            att[(size_t)(q0 + lg * 4 + r) * D + hh * HD + w * 16 + lc] =
                f2bu(oacc[r]);
    } else {
        // =================== big path (nk > 1152 fallback) ===================
        half4v sc[32];
        {
            __builtin_amdgcn_s_setprio(1);
#pragma unroll
            for (int T = 0; T < 32; T++) {
                const int g = 4 * T + w;
                if (g * 16 < nk) {
                    const u16* kp = kbase + (size_t)(g * 16 + lc) * D;
                    floatx4 a = (floatx4)0.f;
                    a = mfma_f16(*(const half8v*)kp,        bq0, a);
                    a = mfma_f16(*(const half8v*)(kp + 32), bq1, a);
                    const int kb0 = g * 16 + lg * 4;
                    half2v p01 = pkrtz(kb0 + 0 < nk ? a[0] * 0.0625f : -30000.f,
                                       kb0 + 1 < nk ? a[1] * 0.0625f : -30000.f);
                    half2v p23 = pkrtz(kb0 + 2 < nk ? a[2] * 0.0625f : -30000.f,
                                       kb0 + 3 < nk ? a[3] * 0.0625f : -30000.f);
                    sc[T] = __builtin_shufflevector(p01, p23, 0, 1, 2, 3);
                } else {
                    sc[T] = NEG4;
                }
            }
            __builtin_amdgcn_s_setprio(0);
        }

        half8v xq[16];
        {
#pragma unroll
            for (int T = 0; T < 16; T++) {
                const int g  = 4 * T + w;
                const int kl = g * 16 + lg * 4;
                const int b  = kl >> 3;
                const int p  = b ^ ((b >> 3) & 7) ^ (lc & 7);
                *(half4v*)&Plds[lc * 1024 + p * 8 + (lg & 1) * 4] = sc[T];
            }
            __syncthreads();
#pragma unroll
            for (int s = 0; s < 8; s++) {
                if (s < NS) {
                    const int b = 16 * s + lc;
                    const int p = b ^ ((b >> 3) & 7) ^ (R & 7);
                    xq[s] = *(const half8v*)&Plds[R * 1024 + p * 8];
                }
            }
            __syncthreads();
#pragma unroll
            for (int T = 16; T < 32; T++) {
                const int g  = 4 * T + w;
                const int kl = g * 16 + lg * 4 - 1024;
                const int b  = kl >> 3;
                const int p  = b ^ ((b >> 3) & 7) ^ (lc & 7);
                *(half4v*)&Plds[lc * 1024 + p * 8 + (lg & 1) * 4] = sc[T];
            }
            __syncthreads();
#pragma unroll
            for (int s = 0; s < 8; s++) {
                const int j = 8 + s;
                if (j < NS) {
                    const int b = 16 * s + lc;
                    const int p = b ^ ((b >> 3) & 7) ^ (R & 7);
                    xq[j] = *(const half8v*)&Plds[R * 1024 + p * 8];
                }
            }
        }

        float tau;
        {
            half8v m8 = xq[0];
#pragma unroll
            for (int i = 1; i < 16; i++)
                if (i < NS) m8 = __builtin_elementwise_max(m8, xq[i]);
            union { half8v v; half2v h[4]; } u; u.v = m8;
            half2v m2 = __builtin_elementwise_max(
                __builtin_elementwise_max(u.h[0], u.h[1]),
                __builtin_elementwise_max(u.h[2], u.h[3]));
            float mx = fmaxf((float)m2[0], (float)m2[1]);
            mx = rowmax16(mx);
            tau = mx - 1.0f;
        }

        const float nact = (float)(8 * NS);
#pragma unroll 1
        for (int it = 0; it < 12; it++) {
            const _Float16 th = (_Float16)tau;
            const float tf = (float)th;
            const half8v t8 = {th, th, th, th, th, th, th, th};
            float m1a = 0.f, m1b = 0.f, m2a = 0.f, m2b = 0.f;
#pragma unroll
            for (int i = 0; i < 16; i++) {
                if (i < NS) {
                    union { half8v v; half2v h[4]; } u;
                    u.v = __builtin_elementwise_max(xq[i], t8);
                    m1a = fdot2f(u.h[0], one2, m1a);
                    m2a = fdot2f(u.h[0], u.h[0], m2a);
                    m1b = fdot2f(u.h[1], one2, m1b);
                    m2b = fdot2f(u.h[1], u.h[1], m2b);
                    m1a = fdot2f(u.h[2], one2, m1a);
                    m2a = fdot2f(u.h[2], u.h[2], m2a);
                    m1b = fdot2f(u.h[3], one2, m1b);
                    m2b = fdot2f(u.h[3], u.h[3], m2b);
                }
            }
            const float M1 = m1a + m1b, M2 = m2a + m2b;
            float s1 = fmaf(-nact, tf, M1);
            float s2 = fmaf(tf, fmaf(nact, tf, -2.f * M1), M2);
            s1 = rowsum16(s1);
            s2 = rowsum16(s2);
            const float delta = (s2 - 1.0f) / (2.0f * fmaxf(s1, 1e-4f));
            tau += delta;
            if (__all(fabsf(delta) < 2.5e-4f)) break;
        }

        const _Float16 th = (_Float16)tau;
        const half8v t8 = {th, th, th, th, th, th, th, th};
        const half8v z8 = (half8v)(_Float16)0.f;
        floatx4 oa0 = (floatx4)0.f, oa1 = (floatx4)0.f;
        floatx4 oa2 = (floatx4)0.f, oa3 = (floatx4)0.f;
#pragma unroll
        for (int s = 0; s < 8; s++) {
            if (s < NS) {
                half8v dp = __builtin_elementwise_max(xq[s] - t8, z8);
                const int b = 16 * s + lc;
                const int p = b ^ ((b >> 3) & 7) ^ (R & 7);
                *(half8v*)&Plds[R * 1024 + p * 8] = dp * dp;
            }
        }
        __syncthreads();
        __builtin_amdgcn_s_setprio(1);
#pragma unroll
        for (int kt = 0; kt < 32; kt++) {
            if (kt < NT) {
                const int b = kt * 4 + lg;
                const int p = b ^ ((b >> 3) & 7) ^ (lc & 7);
                half8v af = *(const half8v*)&Plds[lc * 1024 + p * 8];
                half8v bf = *(const half8v*)(vp + kt * 32);
                if ((kt & 3) == 0)      oa0 = mfma_f16(af, bf, oa0);
                else if ((kt & 3) == 1) oa1 = mfma_f16(af, bf, oa1);
                else if ((kt & 3) == 2) oa2 = mfma_f16(af, bf, oa2);
                else                    oa3 = mfma_f16(af, bf, oa3);
            }
        }
        __builtin_amdgcn_s_setprio(0);
        {
            __syncthreads();
#pragma unroll
            for (int s = 0; s < 8; s++) {
                const int j = 8 + s;
                if (j < NS) {
                    half8v dp = __builtin_elementwise_max(xq[j] - t8, z8);
                    const int b = 16 * s + lc;
                    const int p = b ^ ((b >> 3) & 7) ^ (R & 7);
                    *(half8v*)&Plds[R * 1024 + p * 8] = dp * dp;
                }
            }
            __syncthreads();
            const u16* vph = vp + 1024;
            __builtin_amdgcn_s_setprio(1);
#pragma unroll
            for (int kt = 0; kt < 32; kt++) {
                if (32 + kt < NT) {
                    const int b = kt * 4 + lg;
                    const int p = b ^ ((b >> 3) & 7) ^ (lc & 7);
                    half8v af = *(const half8v*)&Plds[lc * 1024 + p * 8];
                    half8v bf = *(const half8v*)(vph + kt * 32);
                    if ((kt & 3) == 0)      oa0 = mfma_f16(af, bf, oa0);
                    else if ((kt & 3) == 1) oa1 = mfma_f16(af, bf, oa1);
                    else if ((kt & 3) == 2) oa2 = mfma_f16(af, bf, oa2);
                    else                    oa3 = mfma_f16(af, bf, oa3);
                }
            }
            __builtin_amdgcn_s_setprio(0);
        }
        const floatx4 oacc = (oa0 + oa1) + (oa2 + oa3);
#pragma unroll
        for (int r = 0; r < 4; r++)
            att[(size_t)(q0 + lg * 4 + r) * D + hh * HD + w * 16 + lc] =
                f2bu(oacc[r]);
    }
}

// ---------------- host side ---------------------------------------------------
extern "C" void kernel_launch(void* const* d_in, const int* in_sizes, int n_in,
                              void* d_out, int out_size, void* d_ws, size_t ws_size,
                              hipStream_t stream)
{
    const float* inp  = (const float*)d_in[0];
    const int*   mask = (const int*)d_in[1];
    const float* wq   = (const float*)d_in[2];
    const float* bq   = (const float*)d_in[3];
    const float* wk   = (const float*)d_in[4];
    const float* bk   = (const float*)d_in[5];
    const float* wv   = (const float*)d_in[6];
    const float* bv   = (const float*)d_in[7];
    const float* wo   = (const float*)d_in[8];
    const float* bo   = (const float*)d_in[9];
    const float* ln1a = (const float*)d_in[10];
    const float* ln1b = (const float*)d_in[11];
    const float* w1   = (const float*)d_in[12];
    const float* b1   = (const float*)d_in[13];
    const float* w2   = (const float*)d_in[14];
    const float* b2   = (const float*)d_in[15];
    const float* ln2a = (const float*)d_in[16];
    const float* ln2b = (const float*)d_in[17];

    const size_t MB = 1u << 20;
    char* w = (char*)d_ws;
    // 32 MB overlay (16-bit bufs unless noted):
    //  [0,8):  wqkvb(6MB) -> w1b (after QKV) -> w2b fallback (after FFN1)
    //  [8,12): x1 -> att -> x2   (bf16)
    //  [12,16): qb_ (f16) -> yb (bf16)
    //  [16,20): kb_ (f16)  \
    //  [20,24): vTb (f16)   > dead after attn -> hb [16,32)
    //  [24,26): wob (bf16) /  (dead after WO, before FFN1 writes hb)
    //  [26, 26MB+8KB+4): newpos int[2048] + nk  (dead before FFN1 writes hb)
    //  [32,40): w2b early (only if ws_size >= 40MB)
    u16* wqkvb = (u16*)(w + 0 * MB);
    u16* w1b   = (u16*)(w + 0 * MB);
    u16* x1    = (u16*)(w + 8 * MB);
    u16* att   = x1;
    u16* x2    = x1;
    u16* qb_   = (u16*)(w + 12 * MB);
    u16* yb    = (u16*)(w + 12 * MB);
    u16* kb_   = (u16*)(w + 16 * MB);
    u16* vTb   = (u16*)(w + 20 * MB);
    u16* wob   = (u16*)(w + 24 * MB);
    u16* hb    = (u16*)(w + 16 * MB);
    int* np    = (int*)(w + 26 * MB);
    int* nkbuf = np + 2048;
    float* outF = (float*)d_out;

    const bool w2early = (ws_size >= 40 * MB);
    u16* w2b = w2early ? (u16*)(w + 32 * MB) : (u16*)(w + 0 * MB);

    // 0. prep: scan + wq/wk/wv/wo cvts + LN1 (+ early w2 cvt if space)
    prep_kernel<<<w2early ? 10241 : 6145, 256, 0, stream>>>(
        mask, np, nkbuf, wq, wk, wv, wo, wqkvb, wob,
        inp, ln1a, ln1b, x1, w2, w2b);
    // 1. fused QKV projection -> f16 Q [S,D]; K [S,D], V^T [D,S] permuted
    gemm_qkv<<<dim3(3 * D / 128, S / 128), 256, 0, stream>>>(
        x1, wqkvb, bq, bk, bv, np, qb_, kb_, vTb);
    // 2. unified attention (small/big internal) + cvt-w1 tail blocks
    attn_cvt<<<2048 + 4096, 256, 0, stream>>>(qb_, kb_, vTb, nkbuf, att,
                                              w1, w1b);
    // 3. WO projection + residual(inp fp32) -> yb bf16  (64x64: 512 blocks)
    gemm64<1, 1><<<dim3(D / 64, S / 64), 256, 0, stream>>>(
        att, wob, bo, inp, yb, S, D, D);
    // 4. LN2 -> x2 (att dead)
    ln_kernel<u16><<<S, 256, 0, stream>>>(yb, ln2a, ln2b, x2);
    // 5. FFN1 (+ReLU) -> hb bf16 (kb_/vTb/wob/np dead)
    gemm_mfma<1, true, 0><<<dim3(DFF / 128, S / 128), 256, 0, stream>>>(
        x2, w1b, b1, nullptr, hb, S, DFF, D);
    // 6. convert w2 (fallback only: w1b dead now, w2b aliases [0,8))
    if (!w2early)
        cvt_kernel<<<4096, 256, 0, stream>>>(w2, w2b, (DFF * D) / 4);
    // 7. FFN2 + residual(yb bf16) -> fp32 out  (64x64: 512 blocks)
    gemm64<0, 2><<<dim3(D / 64, S / 64), 256, 0, stream>>>(
        hb, w2b, b2, yb, outF, S, D, DFF);
}